// Round 4
// baseline (1167.756 us; speedup 1.0000x reference)
//
#include <hip/hip_runtime.h>
#include <hip/hip_bf16.h>

typedef unsigned int u32;
typedef unsigned short u16;

__device__ __forceinline__ float bf2f(u32 u) {
  union { u32 i; float f; } v; v.i = u << 16; return v.f;
}
__device__ __forceinline__ float sigf(float x) {
  return 1.0f / (1.0f + __expf(-x));
}
__device__ __forceinline__ float tanhfast(float x) {
  return 2.0f / (1.0f + __expf(-2.0f * x)) - 1.0f;
}
__device__ __forceinline__ u16 f2bf(float f) {
  u32 u = __float_as_uint(f);
  u += 0x7fffu + ((u >> 16) & 1u);
  return (u16)(u >> 16);
}

// ---- runtime dtype detection (bf16 vs fp32 inputs) ----
__global__ void k_detect(const u32* __restrict__ w, int* __restrict__ flag) {
  __shared__ int cnt;
  if (threadIdx.x == 0) cnt = 0;
  __syncthreads();
  int c = 0;
  for (int i = threadIdx.x; i < 8192; i += 256) {
    const u32 lo = w[i] & 0xffffu;
    const u32 e = (lo >> 7) & 0xffu;
    c += (e >= 100u && e <= 140u) ? 1 : 0;
  }
  atomicAdd(&cnt, c);
  __syncthreads();
  if (threadIdx.x == 0) *flag = (cnt > 4915) ? 1 : 0;
}

struct Job { const void* s; float* d; int n; };
struct Jobs { Job j[26]; };

__global__ void k_cvt_all(Jobs J, const int* __restrict__ flag) {
  const Job jb = J.j[blockIdx.y];
  const int isbf = *flag;
  for (int i = blockIdx.x * 256 + threadIdx.x; i < jb.n; i += 32 * 256) {
    jb.d[i] = isbf ? bf2f(((const u16*)jb.s)[i]) : ((const float*)jb.s)[i];
  }
}

__global__ void k_init(const float* __restrict__ bias, float* __restrict__ C, int n, int mask) {
  int i = blockIdx.x * 256 + threadIdx.x;
  if (i < n) C[i] = bias[i & mask];
}

// C[M,N] (+)= A[M,K] @ W[N,K]^T (+bias). Unchanged (passes, not yet the bottleneck).
__launch_bounds__(256)
__global__ void k_gemm(const float* __restrict__ A, int lda,
                       const void* __restrict__ Wv, int ldw,
                       const float* __restrict__ bias,
                       float* __restrict__ C, int ldc,
                       int K, int actA, int atom, int wfollow,
                       const int* __restrict__ dflag)
{
  __shared__ float As[16][65];
  __shared__ float Ws[16][65];
  const int isbf = wfollow ? *dflag : 0;
  const int tid = threadIdx.x;
  const int tx = tid & 15, ty = tid >> 4;
  const int m0 = blockIdx.x * 64, n0 = blockIdx.y * 64;
  const int kc = K / gridDim.z;
  const int k0 = blockIdx.z * kc;
  const int lr = tid >> 2;
  const int lk = (tid & 3) << 2;
  float acc[4][4] = {{0.f}};
  const float* Ap   = A + (size_t)(m0 + lr) * lda + k0 + lk;
  const u16*   Wp16 = (const u16*)Wv   + (size_t)(n0 + lr) * ldw + k0 + lk;
  const float* Wp32 = (const float*)Wv + (size_t)(n0 + lr) * ldw + k0 + lk;
  for (int kk = 0; kk < kc; kk += 16) {
    float4 av = *(const float4*)(Ap + kk);
    float w0, w1, w2, w3;
    if (isbf) {
      ushort4 wv = *(const ushort4*)(Wp16 + kk);
      w0 = bf2f(wv.x); w1 = bf2f(wv.y); w2 = bf2f(wv.z); w3 = bf2f(wv.w);
    } else {
      float4 wv = *(const float4*)(Wp32 + kk);
      w0 = wv.x; w1 = wv.y; w2 = wv.z; w3 = wv.w;
    }
    if (actA) {
      av.x = tanhfast(av.x); av.y = tanhfast(av.y);
      av.z = tanhfast(av.z); av.w = tanhfast(av.w);
    }
    __syncthreads();
    As[lk+0][lr] = av.x; As[lk+1][lr] = av.y;
    As[lk+2][lr] = av.z; As[lk+3][lr] = av.w;
    Ws[lk+0][lr] = w0; Ws[lk+1][lr] = w1;
    Ws[lk+2][lr] = w2; Ws[lk+3][lr] = w3;
    __syncthreads();
    #pragma unroll
    for (int k = 0; k < 16; ++k) {
      float a[4], w[4];
      #pragma unroll
      for (int i = 0; i < 4; ++i) a[i] = As[k][ty + 16*i];
      #pragma unroll
      for (int j = 0; j < 4; ++j) w[j] = Ws[k][tx + 16*j];
      #pragma unroll
      for (int i = 0; i < 4; ++i)
        #pragma unroll
        for (int j = 0; j < 4; ++j)
          acc[i][j] = fmaf(a[i], w[j], acc[i][j]);
    }
  }
  #pragma unroll
  for (int i = 0; i < 4; ++i) {
    const int m = m0 + ty + 16*i;
    #pragma unroll
    for (int j = 0; j < 4; ++j) {
      const int n = n0 + tx + 16*j;
      if (atom) atomicAdd(&C[(size_t)m*ldc + n], acc[i][j]);
      else {
        const float bv = bias ? bias[n] : 0.0f;
        C[(size_t)m*ldc + n] = acc[i][j] + bv;
      }
    }
  }
}

// Recurrence, 1024 threads: thread (r=tid>>1, kh=tid&1) owns one gate row x
// half-K -> w[64] persistent (fits the 128-VGPR cap at 4 waves/SIMD; no
// spill/sinking). h broadcast from LDS; one shfl_xor(1) reduce.
__launch_bounds__(1024, 4)
__global__ void k_rec(const float* __restrict__ Zf, const float* __restrict__ Zb,
                      const float* __restrict__ Wf, const float* __restrict__ Wb,
                      float* __restrict__ HS, int hstride, int offF, int offB,
                      float* __restrict__ Cout)
{
  const int b = blockIdx.x & 63;
  const int dir = blockIdx.x >> 6;
  const float* Z = dir ? Zb : Zf;
  const float* Wg = dir ? Wb : Wf;
  const int off = dir ? offB : offF;
  const int tid = threadIdx.x;
  const int r = tid >> 1, kh = tid & 1;

  __shared__ __align__(16) float hlds[128];
  __shared__ float zlds[512];

  float w[64];
  {
    const float4* wr = (const float4*)(Wg + (size_t)r * 128 + kh * 64);
    #pragma unroll
    for (int q = 0; q < 16; ++q) {
      const float4 u = wr[q];
      w[q*4+0]=u.x; w[q*4+1]=u.y; w[q*4+2]=u.z; w[q*4+3]=u.w;
    }
  }
  float creg = 0.0f;
  if (tid < 128) hlds[tid] = 0.0f;
  float zc = Z[((size_t)(dir ? 63 : 0)*64 + b)*512 + r];
  __syncthreads();

  for (int t = 0; t < 64; ++t) {
    const int s = dir ? (63 - t) : t;
    float zn = 0.0f;
    if (t < 63) {
      const int s2 = dir ? (62 - t) : (t + 1);
      zn = Z[((size_t)s2*64 + b)*512 + r];
    }
    float a0 = 0.0f, a1 = 0.0f;
    #pragma unroll
    for (int q = 0; q < 16; q += 2) {
      const float4 ha = *(const float4*)&hlds[kh*64 + q*4];
      const float4 hb = *(const float4*)&hlds[kh*64 + q*4 + 4];
      a0 = fmaf(w[q*4+0], ha.x, a0);
      a0 = fmaf(w[q*4+1], ha.y, a0);
      a0 = fmaf(w[q*4+2], ha.z, a0);
      a0 = fmaf(w[q*4+3], ha.w, a0);
      a1 = fmaf(w[q*4+4], hb.x, a1);
      a1 = fmaf(w[q*4+5], hb.y, a1);
      a1 = fmaf(w[q*4+6], hb.z, a1);
      a1 = fmaf(w[q*4+7], hb.w, a1);
    }
    float acc = a0 + a1;
    acc += __shfl_xor(acc, 1, 64);
    if (kh == 0) zlds[r] = acc + zc;
    __syncthreads();
    if (tid < 128) {
      const float zi = zlds[tid], zf = zlds[tid+128], zg = zlds[tid+256], zo = zlds[tid+384];
      const float cc = sigf(zf) * creg + sigf(zi) * tanhfast(zg);
      const float hh = sigf(zo) * tanhfast(cc);
      creg = cc;
      hlds[tid] = hh;
      HS[((size_t)s*64 + b)*hstride + off + tid] = hh;
    }
    __syncthreads();
    zc = zn;
  }
  if (Cout != nullptr && tid < 128) Cout[b*128 + tid] = creg;
}

// Decoder, 1024 threads. Cell: w[64]/thread (Wih+Whh pre-summed; xin==h_prev).
// attW in LDS (bf16). hproj/scores/ctx spread across all 1024 threads.
#define EPS 136   // ep_b row stride (u16)
#define ENS 129   // enc_b row stride (f32)
#define APS 136   // attWl row stride (u16)
__launch_bounds__(1024, 4)
__global__ void k_dec(const float* __restrict__ enco, const float* __restrict__ encp,
                      const float* __restrict__ ec,
                      const float* __restrict__ Wih, const float* __restrict__ Whh,
                      const float* __restrict__ db, const float* __restrict__ attW,
                      const float* __restrict__ attw, float* __restrict__ flat)
{
  const int b = blockIdx.x;
  const int tid = threadIdx.x;
  const int r = tid >> 1, kh = tid & 1;            // cell role
  const int r8 = tid >> 3, ko = tid & 7;           // hproj / ctx roles
  const int sidx = tid >> 4, ks = tid & 15;        // scores role

  __shared__ __align__(16) float hlds[128];
  __shared__ float zlds[512];
  __shared__ float enc_b[64*ENS];                  // 33 KB
  __shared__ __align__(16) u16 ep_b[64*EPS];       // 17 KB
  __shared__ __align__(16) u16 attWl[128*APS];     // 35 KB
  __shared__ __align__(16) float hproj[128];
  __shared__ float awt[128];
  __shared__ float scores[64];
  __shared__ float awlds[64];

  for (int i = tid; i < 64*128; i += 1024) {
    const int s = i >> 7, k = i & 127;
    const size_t g = ((size_t)s*64 + b)*128 + k;
    enc_b[s*ENS + k] = enco[g];
    ep_b[s*EPS + k] = f2bf(encp[g]);
  }
  for (int i = tid; i < 128*128; i += 1024) {
    attWl[(i >> 7)*APS + (i & 127)] = f2bf(attW[i]);
  }
  if (tid < 128) awt[tid] = attw[tid];

  float w[64];
  {
    const float4* wi = (const float4*)(Wih + (size_t)r*128 + kh*64);
    const float4* wh = (const float4*)(Whh + (size_t)r*128 + kh*64);
    #pragma unroll
    for (int q = 0; q < 16; ++q) {
      const float4 a4 = wi[q], c4 = wh[q];
      w[q*4+0]=a4.x+c4.x; w[q*4+1]=a4.y+c4.y;
      w[q*4+2]=a4.z+c4.z; w[q*4+3]=a4.w+c4.w;
    }
  }
  const float bq = db[r];
  float creg = 0.0f;
  if (tid < 128) {
    hlds[tid] = enco[((size_t)63*64 + b)*128 + tid];
    creg = ec[b*128 + tid];
  }
  __syncthreads();

  for (int t = 0; t < 64; ++t) {
    // --- cell: z = (Wih+Whh) h + b ---
    float a0 = 0.0f, a1 = 0.0f;
    #pragma unroll
    for (int q = 0; q < 16; q += 2) {
      const float4 ha = *(const float4*)&hlds[kh*64 + q*4];
      const float4 hb = *(const float4*)&hlds[kh*64 + q*4 + 4];
      a0 = fmaf(w[q*4+0], ha.x, a0);
      a0 = fmaf(w[q*4+1], ha.y, a0);
      a0 = fmaf(w[q*4+2], ha.z, a0);
      a0 = fmaf(w[q*4+3], ha.w, a0);
      a1 = fmaf(w[q*4+4], hb.x, a1);
      a1 = fmaf(w[q*4+5], hb.y, a1);
      a1 = fmaf(w[q*4+6], hb.z, a1);
      a1 = fmaf(w[q*4+7], hb.w, a1);
    }
    float acc = a0 + a1;
    acc += __shfl_xor(acc, 1, 64);
    if (kh == 0) zlds[r] = acc + bq;
    __syncthreads();
    // --- gates ---
    if (tid < 128) {
      const float zi = zlds[tid], zf2 = zlds[tid+128], zg = zlds[tid+256], zo = zlds[tid+384];
      const float cc = sigf(zf2) * creg + sigf(zi) * tanhfast(zg);
      const float hh = sigf(zo) * tanhfast(cc);
      creg = cc;
      hlds[tid] = hh;
      flat[(size_t)b*16384 + t*256 + tid] = hh;
    }
    __syncthreads();
    // --- hproj: 128 rows x 8 k-slices of 16 ---
    {
      const uint4* aw16 = (const uint4*)&attWl[r8*APS + ko*16];
      const uint4 aA = aw16[0], aB = aw16[1];
      const float4 h0 = *(const float4*)&hlds[ko*16];
      const float4 h1 = *(const float4*)&hlds[ko*16 + 4];
      const float4 h2 = *(const float4*)&hlds[ko*16 + 8];
      const float4 h3 = *(const float4*)&hlds[ko*16 + 12];
      float hp = 0.0f;
      hp = fmaf(bf2f(aA.x & 0xffffu), h0.x, hp);
      hp = fmaf(bf2f(aA.x >> 16),     h0.y, hp);
      hp = fmaf(bf2f(aA.y & 0xffffu), h0.z, hp);
      hp = fmaf(bf2f(aA.y >> 16),     h0.w, hp);
      hp = fmaf(bf2f(aA.z & 0xffffu), h1.x, hp);
      hp = fmaf(bf2f(aA.z >> 16),     h1.y, hp);
      hp = fmaf(bf2f(aA.w & 0xffffu), h1.z, hp);
      hp = fmaf(bf2f(aA.w >> 16),     h1.w, hp);
      hp = fmaf(bf2f(aB.x & 0xffffu), h2.x, hp);
      hp = fmaf(bf2f(aB.x >> 16),     h2.y, hp);
      hp = fmaf(bf2f(aB.y & 0xffffu), h2.z, hp);
      hp = fmaf(bf2f(aB.y >> 16),     h2.w, hp);
      hp = fmaf(bf2f(aB.z & 0xffffu), h3.x, hp);
      hp = fmaf(bf2f(aB.z >> 16),     h3.y, hp);
      hp = fmaf(bf2f(aB.w & 0xffffu), h3.z, hp);
      hp = fmaf(bf2f(aB.w >> 16),     h3.w, hp);
      hp += __shfl_down(hp, 4, 8);
      hp += __shfl_down(hp, 2, 8);
      hp += __shfl_down(hp, 1, 8);
      if (ko == 0) hproj[r8] = hp;
    }
    __syncthreads();
    // --- scores: 64 s x 16 k-slices of 8 ---
    {
      const uint4 e0 = *(const uint4*)&ep_b[sidx*EPS + ks*8];
      const float4 h0 = *(const float4*)&hproj[ks*8];
      const float4 h1 = *(const float4*)&hproj[ks*8 + 4];
      const float4 w0 = *(const float4*)&awt[ks*8];
      const float4 w1 = *(const float4*)&awt[ks*8 + 4];
      float pacc = 0.0f;
      pacc = fmaf(w0.x, tanhfast(h0.x + bf2f(e0.x & 0xffffu)), pacc);
      pacc = fmaf(w0.y, tanhfast(h0.y + bf2f(e0.x >> 16)), pacc);
      pacc = fmaf(w0.z, tanhfast(h0.z + bf2f(e0.y & 0xffffu)), pacc);
      pacc = fmaf(w0.w, tanhfast(h0.w + bf2f(e0.y >> 16)), pacc);
      pacc = fmaf(w1.x, tanhfast(h1.x + bf2f(e0.z & 0xffffu)), pacc);
      pacc = fmaf(w1.y, tanhfast(h1.y + bf2f(e0.z >> 16)), pacc);
      pacc = fmaf(w1.z, tanhfast(h1.z + bf2f(e0.w & 0xffffu)), pacc);
      pacc = fmaf(w1.w, tanhfast(h1.w + bf2f(e0.w >> 16)), pacc);
      pacc += __shfl_down(pacc, 8, 16);
      pacc += __shfl_down(pacc, 4, 16);
      pacc += __shfl_down(pacc, 2, 16);
      pacc += __shfl_down(pacc, 1, 16);
      if (ks == 0) scores[sidx] = pacc;
    }
    __syncthreads();
    // --- softmax over S (wave 0) ---
    if (tid < 64) {
      const float x = scores[tid];
      float m = x;
      #pragma unroll
      for (int d2 = 32; d2 >= 1; d2 >>= 1) m = fmaxf(m, __shfl_xor(m, d2, 64));
      const float e = __expf(x - m);
      float ssum = e;
      #pragma unroll
      for (int d2 = 32; d2 >= 1; d2 >>= 1) ssum += __shfl_xor(ssum, d2, 64);
      awlds[tid] = e / ssum;
    }
    __syncthreads();
    // --- ctx: 128 rows x 8 s-slices of 8; no trailing barrier needed ---
    {
      float cx = 0.0f;
      #pragma unroll
      for (int i = 0; i < 8; ++i) {
        const int s2 = ko*8 + i;
        cx = fmaf(awlds[s2], enc_b[s2*ENS + r8], cx);
      }
      cx += __shfl_down(cx, 4, 8);
      cx += __shfl_down(cx, 2, 8);
      cx += __shfl_down(cx, 1, 8);
      if (ko == 0) flat[(size_t)b*16384 + t*256 + 128 + r8] = cx;
    }
  }
}

__global__ void k_head(const float* __restrict__ a4, const float* __restrict__ outW,
                       const float* __restrict__ outb, void* __restrict__ out,
                       const int* __restrict__ dflag)
{
  const int b = threadIdx.x;
  float acc = outb[0];
  #pragma unroll 8
  for (int k = 0; k < 128; ++k)
    acc = fmaf(outW[k], tanhfast(a4[b*128 + k]), acc);
  if (*dflag) ((u16*)out)[b] = f2bf(acc);
  else        ((float*)out)[b] = acc;
}

extern "C" void kernel_launch(void* const* d_in, const int* in_sizes, int n_in,
                              void* d_out, int out_size, void* d_ws, size_t ws_size,
                              hipStream_t stream)
{
  (void)in_sizes; (void)n_in; (void)out_size; (void)ws_size;

  float* p = (float*)d_ws;
  int*   flagp = (int*)p;    p += 64;
  float* x0    = p; p += 64*64*64;
  float* cl1Wih = p; p += 512*64;
  float* cl1Whh = p; p += 512*128;
  float* cl1b   = p; p += 512;
  float* c2fWih = p; p += 512*128;
  float* c2fWhh = p; p += 512*128;
  float* c2fb   = p; p += 512;
  float* c2bWih = p; p += 512*128;
  float* c2bWhh = p; p += 512*128;
  float* c2bb   = p; p += 512;
  float* c3fWih = p; p += 512*256;
  float* c3fWhh = p; p += 512*128;
  float* c3fb   = p; p += 512;
  float* c3bWih = p; p += 512*256;
  float* c3bWhh = p; p += 512*128;
  float* c3bb   = p; p += 512;
  float* ceWih  = p; p += 512*256;
  float* ceWhh  = p; p += 512*128;
  float* ceb    = p; p += 512;
  float* cdWih  = p; p += 512*128;
  float* cdWhh  = p; p += 512*128;
  float* cdb    = p; p += 512;
  float* cattW  = p; p += 128*128;
  float* cattw  = p; p += 128;
  float* cW1b   = p; p += 1024;
  float* cW2b   = p; p += 512;
  float* cW3b   = p; p += 256;
  float* cW4b   = p; p += 128;
  float* coW    = p; p += 128;
  float* cob    = p; p += 16;
  float* Zf   = p; p += 4096*512;
  float* Zb   = p; p += 4096*512;
  float* h1   = p; p += 4096*128;
  float* x2   = p; p += 4096*256;
  float* x3   = p; p += 4096*256;
  float* enco = p; p += 4096*128;
  float* encp = p; p += 4096*128;
  float* ec   = p; p += 64*128;
  float* flat = p; p += 64*16384;
  float* a1   = p; p += 64*1024;
  float* a2   = p; p += 64*512;
  float* a3   = p; p += 64*256;
  float* a4   = p; p += 64*128;

  k_detect<<<1, 256, 0, stream>>>((const u32*)d_in[2], flagp);

  Jobs J;
  int nj = 0;
  auto add = [&](const void* s, float* d, int n) { J.j[nj].s = s; J.j[nj].d = d; J.j[nj].n = n; ++nj; };
  add(d_in[0],  x0,     64*64*64);
  add(d_in[1],  cl1Wih, 512*64);
  add(d_in[2],  cl1Whh, 512*128);
  add(d_in[3],  cl1b,   512);
  add(d_in[4],  c2fWih, 512*128);
  add(d_in[5],  c2fWhh, 512*128);
  add(d_in[6],  c2fb,   512);
  add(d_in[7],  c2bWih, 512*128);
  add(d_in[8],  c2bWhh, 512*128);
  add(d_in[9],  c2bb,   512);
  add(d_in[10], c3fWih, 512*256);
  add(d_in[11], c3fWhh, 512*128);
  add(d_in[12], c3fb,   512);
  add(d_in[13], c3bWih, 512*256);
  add(d_in[14], c3bWhh, 512*128);
  add(d_in[15], c3bb,   512);
  add(d_in[16], ceWih,  512*256);
  add(d_in[17], ceWhh,  512*128);
  add(d_in[18], ceb,    512);
  add(d_in[19], cdWih,  512*128);
  add(d_in[20], cdWhh,  512*128);
  add(d_in[21], cdb,    512);
  add(d_in[22], cattW,  128*128);
  add(d_in[23], cattw,  128);
  add(d_in[25], cW1b,   1024);
  add(d_in[27], cW2b,   512);
  k_cvt_all<<<dim3(32, nj), 256, 0, stream>>>(J, flagp);

  Jobs J2;
  int nj2 = 0;
  auto add2 = [&](const void* s, float* d, int n) { J2.j[nj2].s = s; J2.j[nj2].d = d; J2.j[nj2].n = n; ++nj2; };
  add2(d_in[29], cW3b, 256);
  add2(d_in[31], cW4b, 128);
  add2(d_in[32], coW,  128);
  add2(d_in[33], cob,  1);
  k_cvt_all<<<dim3(4, nj2), 256, 0, stream>>>(J2, flagp);

  // lstm1
  k_gemm<<<dim3(64,8,1), 256, 0, stream>>>(x0, 64, cl1Wih, 64, cl1b, Zf, 512, 64, 0, 0, 0, flagp);
  k_rec<<<64, 1024, 0, stream>>>(Zf, Zf, cl1Whh, cl1Whh, h1, 128, 0, 0, nullptr);

  // biLSTM 2
  k_gemm<<<dim3(64,8,1), 256, 0, stream>>>(h1, 128, c2fWih, 128, c2fb, Zf, 512, 128, 0, 0, 0, flagp);
  k_gemm<<<dim3(64,8,1), 256, 0, stream>>>(h1, 128, c2bWih, 128, c2bb, Zb, 512, 128, 0, 0, 0, flagp);
  k_rec<<<128, 1024, 0, stream>>>(Zf, Zb, c2fWhh, c2bWhh, x2, 256, 0, 128, nullptr);

  // biLSTM 3
  k_gemm<<<dim3(64,8,1), 256, 0, stream>>>(x2, 256, c3fWih, 256, c3fb, Zf, 512, 256, 0, 0, 0, flagp);
  k_gemm<<<dim3(64,8,1), 256, 0, stream>>>(x2, 256, c3bWih, 256, c3bb, Zb, 512, 256, 0, 0, 0, flagp);
  k_rec<<<128, 1024, 0, stream>>>(Zf, Zb, c3fWhh, c3bWhh, x3, 256, 0, 128, nullptr);

  // encoder
  k_gemm<<<dim3(64,8,1), 256, 0, stream>>>(x3, 256, ceWih, 256, ceb, Zf, 512, 256, 0, 0, 0, flagp);
  k_rec<<<64, 1024, 0, stream>>>(Zf, Zf, ceWhh, ceWhh, enco, 128, 0, 0, ec);

  // hoisted attention projection of enc_out
  k_gemm<<<dim3(64,2,1), 256, 0, stream>>>(enco, 128, cattW, 128, nullptr, encp, 128, 128, 0, 0, 0, flagp);

  // decoder + attention -> flat [64, 16384]
  k_dec<<<64, 1024, 0, stream>>>(enco, encp, ec, cdWih, cdWhh, cdb, cattW, cattw, flat);

  // MLP
  k_init<<<(64*1024+255)/256, 256, 0, stream>>>(cW1b, a1, 64*1024, 1023);
  k_gemm<<<dim3(1,16,16), 256, 0, stream>>>(flat, 16384, d_in[24], 16384, nullptr, a1, 1024, 16384, 0, 1, 1, flagp);
  k_init<<<(64*512+255)/256, 256, 0, stream>>>(cW2b, a2, 64*512, 511);
  k_gemm<<<dim3(1,8,4), 256, 0, stream>>>(a1, 1024, d_in[26], 1024, nullptr, a2, 512, 1024, 1, 1, 1, flagp);
  k_init<<<(64*256+255)/256, 256, 0, stream>>>(cW3b, a3, 64*256, 255);
  k_gemm<<<dim3(1,4,4), 256, 0, stream>>>(a2, 512, d_in[28], 512, nullptr, a3, 256, 512, 1, 1, 1, flagp);
  k_init<<<(64*128+255)/256, 256, 0, stream>>>(cW4b, a4, 64*128, 127);
  k_gemm<<<dim3(1,2,2), 256, 0, stream>>>(a3, 256, d_in[30], 256, nullptr, a4, 128, 256, 1, 1, 1, flagp);

  k_head<<<1, 64, 0, stream>>>(a4, coW, cob, d_out, flagp);
}

// Round 5
// 873.781 us; speedup vs baseline: 1.3364x; 1.3364x over previous
//
#include <hip/hip_runtime.h>
#include <hip/hip_bf16.h>

typedef unsigned int u32;
typedef unsigned short u16;

__device__ __forceinline__ float bf2f(u32 u) {
  union { u32 i; float f; } v; v.i = u << 16; return v.f;
}
__device__ __forceinline__ float sigf(float x) {
  return 1.0f / (1.0f + __expf(-x));
}
__device__ __forceinline__ float tanhfast(float x) {
  return 2.0f / (1.0f + __expf(-2.0f * x)) - 1.0f;
}
__device__ __forceinline__ u16 f2bf(float f) {
  u32 u = __float_as_uint(f);
  u += 0x7fffu + ((u >> 16) & 1u);
  return (u16)(u >> 16);
}

// ---- runtime dtype detection (bf16 vs fp32 inputs) ----
__global__ void k_detect(const u32* __restrict__ w, int* __restrict__ flag) {
  __shared__ int cnt;
  if (threadIdx.x == 0) cnt = 0;
  __syncthreads();
  int c = 0;
  for (int i = threadIdx.x; i < 8192; i += 256) {
    const u32 lo = w[i] & 0xffffu;
    const u32 e = (lo >> 7) & 0xffu;
    c += (e >= 100u && e <= 140u) ? 1 : 0;
  }
  atomicAdd(&cnt, c);
  __syncthreads();
  if (threadIdx.x == 0) *flag = (cnt > 4915) ? 1 : 0;
}

struct Job { const void* s; float* d; int n; };
struct Jobs { Job j[26]; };

__global__ void k_cvt_all(Jobs J, const int* __restrict__ flag) {
  const Job jb = J.j[blockIdx.y];
  const int isbf = *flag;
  for (int i = blockIdx.x * 256 + threadIdx.x; i < jb.n; i += 32 * 256) {
    jb.d[i] = isbf ? bf2f(((const u16*)jb.s)[i]) : ((const float*)jb.s)[i];
  }
}

__global__ void k_addw(const float* __restrict__ a, const float* __restrict__ b,
                       float* __restrict__ c, int n) {
  int i = blockIdx.x * 256 + threadIdx.x;
  if (i < n) c[i] = a[i] + b[i];
}

__global__ void k_init(const float* __restrict__ bias, float* __restrict__ C, int n, int mask) {
  int i = blockIdx.x * 256 + threadIdx.x;
  if (i < n) C[i] = bias[i & mask];
}

// C[M,N] (+)= A[M,K] @ W[N,K]^T (+bias).
__launch_bounds__(256)
__global__ void k_gemm(const float* __restrict__ A, int lda,
                       const void* __restrict__ Wv, int ldw,
                       const float* __restrict__ bias,
                       float* __restrict__ C, int ldc,
                       int K, int actA, int atom, int wfollow,
                       const int* __restrict__ dflag)
{
  __shared__ float As[16][65];
  __shared__ float Ws[16][65];
  const int isbf = wfollow ? *dflag : 0;
  const int tid = threadIdx.x;
  const int tx = tid & 15, ty = tid >> 4;
  const int m0 = blockIdx.x * 64, n0 = blockIdx.y * 64;
  const int kc = K / gridDim.z;
  const int k0 = blockIdx.z * kc;
  const int lr = tid >> 2;
  const int lk = (tid & 3) << 2;
  float acc[4][4] = {{0.f}};
  const float* Ap   = A + (size_t)(m0 + lr) * lda + k0 + lk;
  const u16*   Wp16 = (const u16*)Wv   + (size_t)(n0 + lr) * ldw + k0 + lk;
  const float* Wp32 = (const float*)Wv + (size_t)(n0 + lr) * ldw + k0 + lk;
  for (int kk = 0; kk < kc; kk += 16) {
    float4 av = *(const float4*)(Ap + kk);
    float w0, w1, w2, w3;
    if (isbf) {
      ushort4 wv = *(const ushort4*)(Wp16 + kk);
      w0 = bf2f(wv.x); w1 = bf2f(wv.y); w2 = bf2f(wv.z); w3 = bf2f(wv.w);
    } else {
      float4 wv = *(const float4*)(Wp32 + kk);
      w0 = wv.x; w1 = wv.y; w2 = wv.z; w3 = wv.w;
    }
    if (actA) {
      av.x = tanhfast(av.x); av.y = tanhfast(av.y);
      av.z = tanhfast(av.z); av.w = tanhfast(av.w);
    }
    __syncthreads();
    As[lk+0][lr] = av.x; As[lk+1][lr] = av.y;
    As[lk+2][lr] = av.z; As[lk+3][lr] = av.w;
    Ws[lk+0][lr] = w0; Ws[lk+1][lr] = w1;
    Ws[lk+2][lr] = w2; Ws[lk+3][lr] = w3;
    __syncthreads();
    #pragma unroll
    for (int k = 0; k < 16; ++k) {
      float a[4], w[4];
      #pragma unroll
      for (int i = 0; i < 4; ++i) a[i] = As[k][ty + 16*i];
      #pragma unroll
      for (int j = 0; j < 4; ++j) w[j] = Ws[k][tx + 16*j];
      #pragma unroll
      for (int i = 0; i < 4; ++i)
        #pragma unroll
        for (int j = 0; j < 4; ++j)
          acc[i][j] = fmaf(a[i], w[j], acc[i][j]);
    }
  }
  #pragma unroll
  for (int i = 0; i < 4; ++i) {
    const int m = m0 + ty + 16*i;
    #pragma unroll
    for (int j = 0; j < 4; ++j) {
      const int n = n0 + tx + 16*j;
      if (atom) atomicAdd(&C[(size_t)m*ldc + n], acc[i][j]);
      else {
        const float bv = bias ? bias[n] : 0.0f;
        C[(size_t)m*ldc + n] = acc[i][j] + bv;
      }
    }
  }
}

// Recurrence: thread (r=tid>>2, kq=tid&3) owns rows {r+128j} x k-chunk kq.
// Weights PINNED into VGPRs via empty asm (defeats compiler load-sinking,
// which kept VGPR_Count at 64-128 in rounds 3/4 and re-fetched weights every
// step). zmode=1: Z is a constant 512-vector (decoder bias). h0/c0 optional.
__launch_bounds__(512, 1)
__global__ void k_rec(const float* __restrict__ Zf, const float* __restrict__ Zb,
                      const float* __restrict__ Wf, const float* __restrict__ Wb,
                      float* __restrict__ HS, int hstride, int offF, int offB,
                      const float* __restrict__ h0, const float* __restrict__ c0,
                      int zmode, float* __restrict__ Cout)
{
  const int b = blockIdx.x & 63;
  const int dir = blockIdx.x >> 6;
  const float* Z = dir ? Zb : Zf;
  const float* Wg = dir ? Wb : Wf;
  const int off = dir ? offB : offF;
  const int tid = threadIdx.x;
  const int r = tid >> 2, kq = tid & 3;

  __shared__ __align__(16) float hch[4*40];
  __shared__ float zlds[512];

  float w[4][32];
  #pragma unroll
  for (int j = 0; j < 4; ++j) {
    const float* wr = Wg + (size_t)(r + 128*j) * 128 + kq*32;
    #pragma unroll
    for (int q = 0; q < 8; ++q) {
      const float4 u = *(const float4*)(wr + q*4);
      w[j][q*4+0]=u.x; w[j][q*4+1]=u.y; w[j][q*4+2]=u.z; w[j][q*4+3]=u.w;
    }
  }
  #pragma unroll
  for (int j = 0; j < 4; ++j)
    #pragma unroll
    for (int q = 0; q < 32; ++q)
      asm volatile("" : "+v"(w[j][q]));

  float creg = 0.0f;
  if (tid < 128) {
    hch[(tid>>5)*40 + (tid&31)] = h0 ? h0[b*128 + tid] : 0.0f;
    if (c0) creg = c0[b*128 + tid];
  }
  float zc[4];
  {
    const float* zp = zmode ? Z : (Z + ((size_t)(dir ? 63 : 0)*64 + b)*512);
    #pragma unroll
    for (int j = 0; j < 4; ++j) zc[j] = zp[r + 128*j];
  }
  __syncthreads();

  for (int t = 0; t < 64; ++t) {
    const int s = dir ? (63 - t) : t;
    float zn[4] = {0.f,0.f,0.f,0.f};
    if (!zmode && t < 63) {
      const int s2 = dir ? (62 - t) : (t + 1);
      const float* zp = Z + ((size_t)s2*64 + b)*512;
      #pragma unroll
      for (int j = 0; j < 4; ++j) zn[j] = zp[r + 128*j];
    }
    float a[4] = {0.f,0.f,0.f,0.f};
    #pragma unroll
    for (int q = 0; q < 8; ++q) {
      const float4 h4 = *(const float4*)&hch[kq*40 + q*4];
      #pragma unroll
      for (int j = 0; j < 4; ++j) {
        a[j] = fmaf(w[j][q*4+0], h4.x, a[j]);
        a[j] = fmaf(w[j][q*4+1], h4.y, a[j]);
        a[j] = fmaf(w[j][q*4+2], h4.z, a[j]);
        a[j] = fmaf(w[j][q*4+3], h4.w, a[j]);
      }
    }
    #pragma unroll
    for (int j = 0; j < 4; ++j) {
      a[j] += __shfl_xor(a[j], 1, 64);
      a[j] += __shfl_xor(a[j], 2, 64);
    }
    zlds[r + 128*kq] = a[kq] + zc[kq];
    __syncthreads();
    if (tid < 128) {
      const float zi = zlds[tid], zf = zlds[tid+128], zg = zlds[tid+256], zo = zlds[tid+384];
      const float cc = sigf(zf) * creg + sigf(zi) * tanhfast(zg);
      const float hh = sigf(zo) * tanhfast(cc);
      creg = cc;
      hch[(tid>>5)*40 + (tid&31)] = hh;
      HS[((size_t)s*64 + b)*hstride + off + tid] = hh;
    }
    __syncthreads();
    if (!zmode) {
      #pragma unroll
      for (int j = 0; j < 4; ++j) zc[j] = zn[j];
    }
  }
  if (Cout != nullptr && tid < 128) Cout[b*128 + tid] = creg;
}

// Attention, fully parallel over (b, t-slice): scores/softmax/ctx for 16 t's.
// Hproj = Hdec @ attW^T precomputed by k_gemm.
#define TS 132
__launch_bounds__(256, 1)
__global__ void k_att(const float* __restrict__ enco, const float* __restrict__ encp,
                      const float* __restrict__ Hdec, const float* __restrict__ Hproj,
                      const float* __restrict__ attw, float* __restrict__ flat)
{
  const int b = blockIdx.x;
  const int t0 = blockIdx.y * 16;
  const int tid = threadIdx.x;
  __shared__ __align__(16) float ep[64*TS];
  __shared__ __align__(16) float en[64*TS];
  __shared__ __align__(16) float hp[16*TS];
  __shared__ float S[64*17];
  __shared__ float aw[64*17];
  __shared__ __align__(16) float awt[128];

  for (int i = tid; i < 8192; i += 256) {
    const int s = i >> 7, k = i & 127;
    const size_t g = ((size_t)s*64 + b)*128 + k;
    ep[s*TS + k] = encp[g];
    en[s*TS + k] = enco[g];
  }
  for (int i = tid; i < 2048; i += 256) {
    const int t = i >> 7, k = i & 127;
    const size_t g = ((size_t)(t0 + t)*64 + b)*128 + k;
    hp[t*TS + k] = Hproj[g];
    flat[(size_t)b*16384 + (t0 + t)*256 + k] = Hdec[g];
  }
  if (tid < 128) awt[tid] = attw[tid];
  __syncthreads();

  // scores: thread (t = tid&15, sg = tid>>4) -> 4 s values, full-k dots
  {
    const int t = tid & 15, sg = tid >> 4;
    #pragma unroll
    for (int i = 0; i < 4; ++i) {
      const int s = sg*4 + i;
      float acc = 0.f;
      #pragma unroll 8
      for (int k = 0; k < 128; k += 4) {
        const float4 h4 = *(const float4*)&hp[t*TS + k];
        const float4 e4 = *(const float4*)&ep[s*TS + k];
        const float4 w4 = *(const float4*)&awt[k];
        acc = fmaf(w4.x, tanhfast(h4.x + e4.x), acc);
        acc = fmaf(w4.y, tanhfast(h4.y + e4.y), acc);
        acc = fmaf(w4.z, tanhfast(h4.z + e4.z), acc);
        acc = fmaf(w4.w, tanhfast(h4.w + e4.w), acc);
      }
      S[s*17 + t] = acc;
    }
  }
  __syncthreads();
  // softmax over s per t (16 threads)
  if (tid < 16) {
    const int t = tid;
    float m = -1e30f;
    for (int s = 0; s < 64; ++s) m = fmaxf(m, S[s*17 + t]);
    float sum = 0.f;
    for (int s = 0; s < 64; ++s) {
      const float e = __expf(S[s*17 + t] - m);
      aw[s*17 + t] = e;
      sum += e;
    }
    const float inv = 1.0f / sum;
    for (int s = 0; s < 64; ++s) aw[s*17 + t] *= inv;
  }
  __syncthreads();
  // ctx: thread (t = tid>>4, kg = tid&15) -> k = kg*8 .. +8
  {
    const int t = tid >> 4, kg = tid & 15;
    float c0a[8] = {0,0,0,0,0,0,0,0};
    for (int s = 0; s < 64; ++s) {
      const float a = aw[s*17 + t];
      const float4 e0 = *(const float4*)&en[s*TS + kg*8];
      const float4 e1 = *(const float4*)&en[s*TS + kg*8 + 4];
      c0a[0] = fmaf(a, e0.x, c0a[0]);
      c0a[1] = fmaf(a, e0.y, c0a[1]);
      c0a[2] = fmaf(a, e0.z, c0a[2]);
      c0a[3] = fmaf(a, e0.w, c0a[3]);
      c0a[4] = fmaf(a, e1.x, c0a[4]);
      c0a[5] = fmaf(a, e1.y, c0a[5]);
      c0a[6] = fmaf(a, e1.z, c0a[6]);
      c0a[7] = fmaf(a, e1.w, c0a[7]);
    }
    float4 o0 = {c0a[0], c0a[1], c0a[2], c0a[3]};
    float4 o1 = {c0a[4], c0a[5], c0a[6], c0a[7]};
    float* dst = &flat[(size_t)b*16384 + (t0 + t)*256 + 128 + kg*8];
    *(float4*)dst = o0;
    *(float4*)(dst + 4) = o1;
  }
}

__global__ void k_head(const float* __restrict__ a4, const float* __restrict__ outW,
                       const float* __restrict__ outb, void* __restrict__ out,
                       const int* __restrict__ dflag)
{
  const int b = threadIdx.x;
  float acc = outb[0];
  #pragma unroll 8
  for (int k = 0; k < 128; ++k)
    acc = fmaf(outW[k], tanhfast(a4[b*128 + k]), acc);
  if (*dflag) ((u16*)out)[b] = f2bf(acc);
  else        ((float*)out)[b] = acc;
}

extern "C" void kernel_launch(void* const* d_in, const int* in_sizes, int n_in,
                              void* d_out, int out_size, void* d_ws, size_t ws_size,
                              hipStream_t stream)
{
  (void)in_sizes; (void)n_in; (void)out_size; (void)ws_size;

  float* p = (float*)d_ws;
  int*   flagp = (int*)p;    p += 64;
  float* x0    = p; p += 64*64*64;
  float* cl1Wih = p; p += 512*64;
  float* cl1Whh = p; p += 512*128;
  float* cl1b   = p; p += 512;
  float* c2fWih = p; p += 512*128;
  float* c2fWhh = p; p += 512*128;
  float* c2fb   = p; p += 512;
  float* c2bWih = p; p += 512*128;
  float* c2bWhh = p; p += 512*128;
  float* c2bb   = p; p += 512;
  float* c3fWih = p; p += 512*256;
  float* c3fWhh = p; p += 512*128;
  float* c3fb   = p; p += 512;
  float* c3bWih = p; p += 512*256;
  float* c3bWhh = p; p += 512*128;
  float* c3bb   = p; p += 512;
  float* ceWih  = p; p += 512*256;
  float* ceWhh  = p; p += 512*128;
  float* ceb    = p; p += 512;
  float* cdWih  = p; p += 512*128;
  float* cdWhh  = p; p += 512*128;
  float* cdb    = p; p += 512;
  float* cattW  = p; p += 128*128;
  float* cattw  = p; p += 128;
  float* cW1b   = p; p += 1024;
  float* cW2b   = p; p += 512;
  float* cW3b   = p; p += 256;
  float* cW4b   = p; p += 128;
  float* coW    = p; p += 128;
  float* cob    = p; p += 16;
  float* cdWsum = p; p += 512*128;
  float* Zf   = p; p += 4096*512;
  float* Zb   = p; p += 4096*512;
  float* h1   = p; p += 4096*128;
  float* x2   = p; p += 4096*256;
  float* x3   = p; p += 4096*256;
  float* enco = p; p += 4096*128;
  float* encp = p; p += 4096*128;
  float* Hdec = p; p += 4096*128;
  float* Hprj = p; p += 4096*128;
  float* ec   = p; p += 64*128;
  float* flat = p; p += 64*16384;
  float* a1   = p; p += 64*1024;
  float* a2   = p; p += 64*512;
  float* a3   = p; p += 64*256;
  float* a4   = p; p += 64*128;

  k_detect<<<1, 256, 0, stream>>>((const u32*)d_in[2], flagp);

  Jobs J;
  int nj = 0;
  auto add = [&](const void* s, float* d, int n) { J.j[nj].s = s; J.j[nj].d = d; J.j[nj].n = n; ++nj; };
  add(d_in[0],  x0,     64*64*64);
  add(d_in[1],  cl1Wih, 512*64);
  add(d_in[2],  cl1Whh, 512*128);
  add(d_in[3],  cl1b,   512);
  add(d_in[4],  c2fWih, 512*128);
  add(d_in[5],  c2fWhh, 512*128);
  add(d_in[6],  c2fb,   512);
  add(d_in[7],  c2bWih, 512*128);
  add(d_in[8],  c2bWhh, 512*128);
  add(d_in[9],  c2bb,   512);
  add(d_in[10], c3fWih, 512*256);
  add(d_in[11], c3fWhh, 512*128);
  add(d_in[12], c3fb,   512);
  add(d_in[13], c3bWih, 512*256);
  add(d_in[14], c3bWhh, 512*128);
  add(d_in[15], c3bb,   512);
  add(d_in[16], ceWih,  512*256);
  add(d_in[17], ceWhh,  512*128);
  add(d_in[18], ceb,    512);
  add(d_in[19], cdWih,  512*128);
  add(d_in[20], cdWhh,  512*128);
  add(d_in[21], cdb,    512);
  add(d_in[22], cattW,  128*128);
  add(d_in[23], cattw,  128);
  add(d_in[25], cW1b,   1024);
  add(d_in[27], cW2b,   512);
  k_cvt_all<<<dim3(32, nj), 256, 0, stream>>>(J, flagp);

  Jobs J2;
  int nj2 = 0;
  auto add2 = [&](const void* s, float* d, int n) { J2.j[nj2].s = s; J2.j[nj2].d = d; J2.j[nj2].n = n; ++nj2; };
  add2(d_in[29], cW3b, 256);
  add2(d_in[31], cW4b, 128);
  add2(d_in[32], coW,  128);
  add2(d_in[33], cob,  1);
  k_cvt_all<<<dim3(4, nj2), 256, 0, stream>>>(J2, flagp);

  // decoder Wsum = Wih + Whh (xin == h_prev in the reference recurrence)
  k_addw<<<(512*128 + 255)/256, 256, 0, stream>>>(cdWih, cdWhh, cdWsum, 512*128);

  // lstm1
  k_gemm<<<dim3(64,8,1), 256, 0, stream>>>(x0, 64, cl1Wih, 64, cl1b, Zf, 512, 64, 0, 0, 0, flagp);
  k_rec<<<64, 512, 0, stream>>>(Zf, Zf, cl1Whh, cl1Whh, h1, 128, 0, 0, nullptr, nullptr, 0, nullptr);

  // biLSTM 2
  k_gemm<<<dim3(64,8,1), 256, 0, stream>>>(h1, 128, c2fWih, 128, c2fb, Zf, 512, 128, 0, 0, 0, flagp);
  k_gemm<<<dim3(64,8,1), 256, 0, stream>>>(h1, 128, c2bWih, 128, c2bb, Zb, 512, 128, 0, 0, 0, flagp);
  k_rec<<<128, 512, 0, stream>>>(Zf, Zb, c2fWhh, c2bWhh, x2, 256, 0, 128, nullptr, nullptr, 0, nullptr);

  // biLSTM 3
  k_gemm<<<dim3(64,8,1), 256, 0, stream>>>(x2, 256, c3fWih, 256, c3fb, Zf, 512, 256, 0, 0, 0, flagp);
  k_gemm<<<dim3(64,8,1), 256, 0, stream>>>(x2, 256, c3bWih, 256, c3bb, Zb, 512, 256, 0, 0, 0, flagp);
  k_rec<<<128, 512, 0, stream>>>(Zf, Zb, c3fWhh, c3bWhh, x3, 256, 0, 128, nullptr, nullptr, 0, nullptr);

  // encoder
  k_gemm<<<dim3(64,8,1), 256, 0, stream>>>(x3, 256, ceWih, 256, ceb, Zf, 512, 256, 0, 0, 0, flagp);
  k_rec<<<64, 512, 0, stream>>>(Zf, Zf, ceWhh, ceWhh, enco, 128, 0, 0, nullptr, nullptr, 0, ec);

  // decoder recurrence (attention-independent): h0 = enco[63], c0 = ec, Z = bias
  k_rec<<<64, 512, 0, stream>>>(cdb, cdb, cdWsum, cdWsum, Hdec, 128, 0, 0,
                                enco + (size_t)63*64*128, ec, 1, nullptr);

  // hoisted projections: encp = enco@attW^T, Hprj = Hdec@attW^T
  k_gemm<<<dim3(64,2,1), 256, 0, stream>>>(enco, 128, cattW, 128, nullptr, encp, 128, 128, 0, 0, 0, flagp);
  k_gemm<<<dim3(64,2,1), 256, 0, stream>>>(Hdec, 128, cattW, 128, nullptr, Hprj, 128, 128, 0, 0, 0, flagp);

  // attention (parallel over 64 b x 4 t-slices) -> flat [64, 16384]
  k_att<<<dim3(64,4), 256, 0, stream>>>(enco, encp, Hdec, Hprj, cattw, flat);

  // MLP
  k_init<<<(64*1024+255)/256, 256, 0, stream>>>(cW1b, a1, 64*1024, 1023);
  k_gemm<<<dim3(1,16,16), 256, 0, stream>>>(flat, 16384, d_in[24], 16384, nullptr, a1, 1024, 16384, 0, 1, 1, flagp);
  k_init<<<(64*512+255)/256, 256, 0, stream>>>(cW2b, a2, 64*512, 511);
  k_gemm<<<dim3(1,8,4), 256, 0, stream>>>(a1, 1024, d_in[26], 1024, nullptr, a2, 512, 1024, 1, 1, 1, flagp);
  k_init<<<(64*256+255)/256, 256, 0, stream>>>(cW3b, a3, 64*256, 255);
  k_gemm<<<dim3(1,4,4), 256, 0, stream>>>(a2, 512, d_in[28], 512, nullptr, a3, 256, 512, 1, 1, 1, flagp);
  k_init<<<(64*128+255)/256, 256, 0, stream>>>(cW4b, a4, 64*128, 127);
  k_gemm<<<dim3(1,2,2), 256, 0, stream>>>(a3, 256, d_in[30], 256, nullptr, a4, 128, 256, 1, 1, 1, flagp);

  k_head<<<1, 64, 0, stream>>>(a4, coW, cob, d_out, flagp);
}

// Round 6
// 761.378 us; speedup vs baseline: 1.5337x; 1.1476x over previous
//
#include <hip/hip_runtime.h>
#include <hip/hip_bf16.h>

typedef unsigned int u32;
typedef unsigned short u16;

__device__ __forceinline__ float bf2f(u32 u) {
  union { u32 i; float f; } v; v.i = u << 16; return v.f;
}
__device__ __forceinline__ float sigf(float x) {
  return 1.0f / (1.0f + __expf(-x));
}
__device__ __forceinline__ float tanhfast(float x) {
  return 2.0f / (1.0f + __expf(-2.0f * x)) - 1.0f;
}
__device__ __forceinline__ u16 f2bf(float f) {
  u32 u = __float_as_uint(f);
  u += 0x7fffu + ((u >> 16) & 1u);
  return (u16)(u >> 16);
}

// ---- runtime dtype detection (bf16 vs fp32 inputs) ----
__global__ void k_detect(const u32* __restrict__ w, int* __restrict__ flag) {
  __shared__ int cnt;
  if (threadIdx.x == 0) cnt = 0;
  __syncthreads();
  int c = 0;
  for (int i = threadIdx.x; i < 8192; i += 256) {
    const u32 lo = w[i] & 0xffffu;
    const u32 e = (lo >> 7) & 0xffu;
    c += (e >= 100u && e <= 140u) ? 1 : 0;
  }
  atomicAdd(&cnt, c);
  __syncthreads();
  if (threadIdx.x == 0) *flag = (cnt > 4915) ? 1 : 0;
}

struct Job { const void* s; float* d; int n; };
struct Jobs { Job j[26]; };

__global__ void k_cvt_all(Jobs J, const int* __restrict__ flag) {
  const Job jb = J.j[blockIdx.y];
  const int isbf = *flag;
  for (int i = blockIdx.x * 256 + threadIdx.x; i < jb.n; i += 32 * 256) {
    jb.d[i] = isbf ? bf2f(((const u16*)jb.s)[i]) : ((const float*)jb.s)[i];
  }
}

__global__ void k_addw(const float* __restrict__ a, const float* __restrict__ b,
                       float* __restrict__ c, int n) {
  int i = blockIdx.x * 256 + threadIdx.x;
  if (i < n) c[i] = a[i] + b[i];
}

__global__ void k_init(const float* __restrict__ bias, float* __restrict__ C, int n, int mask) {
  int i = blockIdx.x * 256 + threadIdx.x;
  if (i < n) C[i] = bias[i & mask];
}

// C[M,N] (+)= A[M,K] @ W[N,K]^T (+bias). 32-wide K staging, 16 B/lane loads.
// kc (= K/gridDim.z) must be a multiple of 32.
__launch_bounds__(256)
__global__ void k_gemm(const float* __restrict__ A, int lda,
                       const void* __restrict__ Wv, int ldw,
                       const float* __restrict__ bias,
                       float* __restrict__ C, int ldc,
                       int K, int actA, int atom, int wfollow,
                       const int* __restrict__ dflag)
{
  __shared__ float As[32][65];
  __shared__ float Ws[32][65];
  const int isbf = wfollow ? *dflag : 0;
  const int tid = threadIdx.x;
  const int tx = tid & 15, ty = tid >> 4;
  const int m0 = blockIdx.x * 64, n0 = blockIdx.y * 64;
  const int kc = K / gridDim.z;
  const int k0 = blockIdx.z * kc;
  const int lr = tid >> 2;          // 0..63
  const int lk = (tid & 3) << 3;    // 0,8,16,24
  float acc[4][4] = {{0.f}};
  const float* Ap   = A + (size_t)(m0 + lr) * lda + k0 + lk;
  const u16*   Wp16 = (const u16*)Wv   + (size_t)(n0 + lr) * ldw + k0 + lk;
  const float* Wp32 = (const float*)Wv + (size_t)(n0 + lr) * ldw + k0 + lk;
  for (int kk = 0; kk < kc; kk += 32) {
    float4 av0 = *(const float4*)(Ap + kk);
    float4 av1 = *(const float4*)(Ap + kk + 4);
    float wv[8];
    if (isbf) {
      const uint4 wu = *(const uint4*)(Wp16 + kk);
      wv[0]=bf2f(wu.x & 0xffffu); wv[1]=bf2f(wu.x >> 16);
      wv[2]=bf2f(wu.y & 0xffffu); wv[3]=bf2f(wu.y >> 16);
      wv[4]=bf2f(wu.z & 0xffffu); wv[5]=bf2f(wu.z >> 16);
      wv[6]=bf2f(wu.w & 0xffffu); wv[7]=bf2f(wu.w >> 16);
    } else {
      const float4 w0 = *(const float4*)(Wp32 + kk);
      const float4 w1 = *(const float4*)(Wp32 + kk + 4);
      wv[0]=w0.x; wv[1]=w0.y; wv[2]=w0.z; wv[3]=w0.w;
      wv[4]=w1.x; wv[5]=w1.y; wv[6]=w1.z; wv[7]=w1.w;
    }
    if (actA) {
      av0.x = tanhfast(av0.x); av0.y = tanhfast(av0.y);
      av0.z = tanhfast(av0.z); av0.w = tanhfast(av0.w);
      av1.x = tanhfast(av1.x); av1.y = tanhfast(av1.y);
      av1.z = tanhfast(av1.z); av1.w = tanhfast(av1.w);
    }
    __syncthreads();
    As[lk+0][lr] = av0.x; As[lk+1][lr] = av0.y;
    As[lk+2][lr] = av0.z; As[lk+3][lr] = av0.w;
    As[lk+4][lr] = av1.x; As[lk+5][lr] = av1.y;
    As[lk+6][lr] = av1.z; As[lk+7][lr] = av1.w;
    #pragma unroll
    for (int q = 0; q < 8; ++q) Ws[lk+q][lr] = wv[q];
    __syncthreads();
    #pragma unroll
    for (int k = 0; k < 32; ++k) {
      float a[4], w[4];
      #pragma unroll
      for (int i = 0; i < 4; ++i) a[i] = As[k][ty + 16*i];
      #pragma unroll
      for (int j = 0; j < 4; ++j) w[j] = Ws[k][tx + 16*j];
      #pragma unroll
      for (int i = 0; i < 4; ++i)
        #pragma unroll
        for (int j = 0; j < 4; ++j)
          acc[i][j] = fmaf(a[i], w[j], acc[i][j]);
    }
  }
  #pragma unroll
  for (int i = 0; i < 4; ++i) {
    const int m = m0 + ty + 16*i;
    #pragma unroll
    for (int j = 0; j < 4; ++j) {
      const int n = n0 + tx + 16*j;
      if (atom) atomicAdd(&C[(size_t)m*ldc + n], acc[i][j]);
      else {
        const float bv = bias ? bias[n] : 0.0f;
        C[(size_t)m*ldc + n] = acc[i][j] + bv;
      }
    }
  }
}

// Recurrence: thread (r=tid>>2, kq=tid&3) owns rows {r+128j} x k-chunk kq.
// Weights PINNED into VGPRs via empty asm. zmode=1: Z is a constant vector.
// zld = row stride of Z.
__launch_bounds__(512, 1)
__global__ void k_rec(const float* __restrict__ Zf, const float* __restrict__ Zb,
                      const float* __restrict__ Wf, const float* __restrict__ Wb,
                      float* __restrict__ HS, int hstride, int offF, int offB,
                      const float* __restrict__ h0, const float* __restrict__ c0,
                      int zmode, int zld, float* __restrict__ Cout)
{
  const int b = blockIdx.x & 63;
  const int dir = blockIdx.x >> 6;
  const float* Z = dir ? Zb : Zf;
  const float* Wg = dir ? Wb : Wf;
  const int off = dir ? offB : offF;
  const int tid = threadIdx.x;
  const int r = tid >> 2, kq = tid & 3;

  __shared__ __align__(16) float hch[4*40];
  __shared__ float zlds[512];

  float w[4][32];
  #pragma unroll
  for (int j = 0; j < 4; ++j) {
    const float* wr = Wg + (size_t)(r + 128*j) * 128 + kq*32;
    #pragma unroll
    for (int q = 0; q < 8; ++q) {
      const float4 u = *(const float4*)(wr + q*4);
      w[j][q*4+0]=u.x; w[j][q*4+1]=u.y; w[j][q*4+2]=u.z; w[j][q*4+3]=u.w;
    }
  }
  #pragma unroll
  for (int j = 0; j < 4; ++j)
    #pragma unroll
    for (int q = 0; q < 32; ++q)
      asm volatile("" : "+v"(w[j][q]));

  float creg = 0.0f;
  if (tid < 128) {
    hch[(tid>>5)*40 + (tid&31)] = h0 ? h0[b*128 + tid] : 0.0f;
    if (c0) creg = c0[b*128 + tid];
  }
  float zc[4];
  {
    const float* zp = zmode ? Z : (Z + ((size_t)(dir ? 63 : 0)*64 + b)*zld);
    #pragma unroll
    for (int j = 0; j < 4; ++j) zc[j] = zp[r + 128*j];
  }
  __syncthreads();

  for (int t = 0; t < 64; ++t) {
    const int s = dir ? (63 - t) : t;
    float zn[4] = {0.f,0.f,0.f,0.f};
    if (!zmode && t < 63) {
      const int s2 = dir ? (62 - t) : (t + 1);
      const float* zp = Z + ((size_t)s2*64 + b)*zld;
      #pragma unroll
      for (int j = 0; j < 4; ++j) zn[j] = zp[r + 128*j];
    }
    float a[4] = {0.f,0.f,0.f,0.f};
    #pragma unroll
    for (int q = 0; q < 8; ++q) {
      const float4 h4 = *(const float4*)&hch[kq*40 + q*4];
      #pragma unroll
      for (int j = 0; j < 4; ++j) {
        a[j] = fmaf(w[j][q*4+0], h4.x, a[j]);
        a[j] = fmaf(w[j][q*4+1], h4.y, a[j]);
        a[j] = fmaf(w[j][q*4+2], h4.z, a[j]);
        a[j] = fmaf(w[j][q*4+3], h4.w, a[j]);
      }
    }
    #pragma unroll
    for (int j = 0; j < 4; ++j) {
      a[j] += __shfl_xor(a[j], 1, 64);
      a[j] += __shfl_xor(a[j], 2, 64);
    }
    zlds[r + 128*kq] = a[kq] + zc[kq];
    __syncthreads();
    if (tid < 128) {
      const float zi = zlds[tid], zf = zlds[tid+128], zg = zlds[tid+256], zo = zlds[tid+384];
      const float cc = sigf(zf) * creg + sigf(zi) * tanhfast(zg);
      const float hh = sigf(zo) * tanhfast(cc);
      creg = cc;
      hch[(tid>>5)*40 + (tid&31)] = hh;
      HS[((size_t)s*64 + b)*hstride + off + tid] = hh;
    }
    __syncthreads();
    if (!zmode) {
      #pragma unroll
      for (int j = 0; j < 4; ++j) zc[j] = zn[j];
    }
  }
  if (Cout != nullptr && tid < 128) Cout[b*128 + tid] = creg;
}

// Attention, fully parallel over (b, t-slice).
#define TS 132
__launch_bounds__(256, 1)
__global__ void k_att(const float* __restrict__ enco, const float* __restrict__ encp,
                      const float* __restrict__ Hdec, const float* __restrict__ Hproj,
                      const float* __restrict__ attw, float* __restrict__ flat)
{
  const int b = blockIdx.x;
  const int t0 = blockIdx.y * 16;
  const int tid = threadIdx.x;
  __shared__ __align__(16) float ep[64*TS];
  __shared__ __align__(16) float en[64*TS];
  __shared__ __align__(16) float hp[16*TS];
  __shared__ float S[64*17];
  __shared__ float aw[64*17];
  __shared__ __align__(16) float awt[128];

  for (int i = tid; i < 8192; i += 256) {
    const int s = i >> 7, k = i & 127;
    const size_t g = ((size_t)s*64 + b)*128 + k;
    ep[s*TS + k] = encp[g];
    en[s*TS + k] = enco[g];
  }
  for (int i = tid; i < 2048; i += 256) {
    const int t = i >> 7, k = i & 127;
    const size_t g = ((size_t)(t0 + t)*64 + b)*128 + k;
    hp[t*TS + k] = Hproj[g];
    flat[(size_t)b*16384 + (t0 + t)*256 + k] = Hdec[g];
  }
  if (tid < 128) awt[tid] = attw[tid];
  __syncthreads();

  {
    const int t = tid & 15, sg = tid >> 4;
    #pragma unroll
    for (int i = 0; i < 4; ++i) {
      const int s = sg*4 + i;
      float acc = 0.f;
      #pragma unroll 8
      for (int k = 0; k < 128; k += 4) {
        const float4 h4 = *(const float4*)&hp[t*TS + k];
        const float4 e4 = *(const float4*)&ep[s*TS + k];
        const float4 w4 = *(const float4*)&awt[k];
        acc = fmaf(w4.x, tanhfast(h4.x + e4.x), acc);
        acc = fmaf(w4.y, tanhfast(h4.y + e4.y), acc);
        acc = fmaf(w4.z, tanhfast(h4.z + e4.z), acc);
        acc = fmaf(w4.w, tanhfast(h4.w + e4.w), acc);
      }
      S[s*17 + t] = acc;
    }
  }
  __syncthreads();
  if (tid < 16) {
    const int t = tid;
    float m = -1e30f;
    for (int s = 0; s < 64; ++s) m = fmaxf(m, S[s*17 + t]);
    float sum = 0.f;
    for (int s = 0; s < 64; ++s) {
      const float e = __expf(S[s*17 + t] - m);
      aw[s*17 + t] = e;
      sum += e;
    }
    const float inv = 1.0f / sum;
    for (int s = 0; s < 64; ++s) aw[s*17 + t] *= inv;
  }
  __syncthreads();
  {
    const int t = tid >> 4, kg = tid & 15;
    float c0a[8] = {0,0,0,0,0,0,0,0};
    for (int s = 0; s < 64; ++s) {
      const float a = aw[s*17 + t];
      const float4 e0 = *(const float4*)&en[s*TS + kg*8];
      const float4 e1 = *(const float4*)&en[s*TS + kg*8 + 4];
      c0a[0] = fmaf(a, e0.x, c0a[0]);
      c0a[1] = fmaf(a, e0.y, c0a[1]);
      c0a[2] = fmaf(a, e0.z, c0a[2]);
      c0a[3] = fmaf(a, e0.w, c0a[3]);
      c0a[4] = fmaf(a, e1.x, c0a[4]);
      c0a[5] = fmaf(a, e1.y, c0a[5]);
      c0a[6] = fmaf(a, e1.z, c0a[6]);
      c0a[7] = fmaf(a, e1.w, c0a[7]);
    }
    float4 o0 = {c0a[0], c0a[1], c0a[2], c0a[3]};
    float4 o1 = {c0a[4], c0a[5], c0a[6], c0a[7]};
    float* dst = &flat[(size_t)b*16384 + (t0 + t)*256 + 128 + kg*8];
    *(float4*)dst = o0;
    *(float4*)(dst + 4) = o1;
  }
}

__global__ void k_head(const float* __restrict__ a4, const float* __restrict__ outW,
                       const float* __restrict__ outb, void* __restrict__ out,
                       const int* __restrict__ dflag)
{
  const int b = threadIdx.x;
  float acc = outb[0];
  #pragma unroll 8
  for (int k = 0; k < 128; ++k)
    acc = fmaf(outW[k], tanhfast(a4[b*128 + k]), acc);
  if (*dflag) ((u16*)out)[b] = f2bf(acc);
  else        ((float*)out)[b] = acc;
}

extern "C" void kernel_launch(void* const* d_in, const int* in_sizes, int n_in,
                              void* d_out, int out_size, void* d_ws, size_t ws_size,
                              hipStream_t stream)
{
  (void)in_sizes; (void)n_in; (void)out_size; (void)ws_size;

  float* p = (float*)d_ws;
  int*   flagp = (int*)p;    p += 64;
  float* x0    = p; p += 64*64*64;
  float* cl1Wih = p; p += 512*64;
  float* cl1Whh = p; p += 512*128;
  float* cl1b   = p; p += 512;
  float* c2Wih  = p; p += 1024*128;   // f rows 0-511, b rows 512-1023
  float* c2bias = p; p += 1024;       // f | b
  float* c2fWhh = p; p += 512*128;
  float* c2bWhh = p; p += 512*128;
  float* c3Wih  = p; p += 1024*256;   // f | b
  float* c3bias = p; p += 1024;
  float* c3fWhh = p; p += 512*128;
  float* c3bWhh = p; p += 512*128;
  float* ceWih  = p; p += 512*256;
  float* ceWhh  = p; p += 512*128;
  float* ceb    = p; p += 512;
  float* cdWih  = p; p += 512*128;
  float* cdWhh  = p; p += 512*128;
  float* cdb    = p; p += 512;
  float* cattW  = p; p += 128*128;
  float* cattw  = p; p += 128;
  float* cW1b   = p; p += 1024;
  float* cW2b   = p; p += 512;
  float* cW3b   = p; p += 256;
  float* cW4b   = p; p += 128;
  float* coW    = p; p += 128;
  float* cob    = p; p += 16;
  float* cdWsum = p; p += 512*128;
  float* Zf   = p; p += 4096*512;
  float* Z2   = p; p += 4096*1024;
  float* h1   = p; p += 4096*128;
  float* x2   = p; p += 4096*256;
  float* x3   = p; p += 4096*256;
  float* enco = p; p += 4096*128;   // enco and Hdec contiguous (merged proj A)
  float* Hdec = p; p += 4096*128;
  float* encp = p; p += 4096*128;   // encp and Hprj contiguous (merged proj C)
  float* Hprj = p; p += 4096*128;
  float* ec   = p; p += 64*128;
  float* flat = p; p += 64*16384;
  float* a1   = p; p += 64*1024;
  float* a2   = p; p += 64*512;
  float* a3   = p; p += 64*256;
  float* a4   = p; p += 64*128;

  k_detect<<<1, 256, 0, stream>>>((const u32*)d_in[2], flagp);

  Jobs J;
  int nj = 0;
  auto add = [&](const void* s, float* d, int n) { J.j[nj].s = s; J.j[nj].d = d; J.j[nj].n = n; ++nj; };
  add(d_in[0],  x0,     64*64*64);
  add(d_in[1],  cl1Wih, 512*64);
  add(d_in[2],  cl1Whh, 512*128);
  add(d_in[3],  cl1b,   512);
  add(d_in[4],  c2Wih,            512*128);
  add(d_in[7],  c2Wih + 512*128,  512*128);
  add(d_in[6],  c2bias,       512);
  add(d_in[9],  c2bias + 512, 512);
  add(d_in[5],  c2fWhh, 512*128);
  add(d_in[8],  c2bWhh, 512*128);
  add(d_in[10], c3Wih,            512*256);
  add(d_in[13], c3Wih + 512*256,  512*256);
  add(d_in[12], c3bias,       512);
  add(d_in[15], c3bias + 512, 512);
  add(d_in[11], c3fWhh, 512*128);
  add(d_in[14], c3bWhh, 512*128);
  add(d_in[16], ceWih,  512*256);
  add(d_in[17], ceWhh,  512*128);
  add(d_in[18], ceb,    512);
  add(d_in[19], cdWih,  512*128);
  add(d_in[20], cdWhh,  512*128);
  add(d_in[21], cdb,    512);
  add(d_in[22], cattW,  128*128);
  add(d_in[23], cattw,  128);
  add(d_in[25], cW1b,   1024);
  add(d_in[27], cW2b,   512);
  k_cvt_all<<<dim3(32, nj), 256, 0, stream>>>(J, flagp);

  Jobs J2;
  int nj2 = 0;
  auto add2 = [&](const void* s, float* d, int n) { J2.j[nj2].s = s; J2.j[nj2].d = d; J2.j[nj2].n = n; ++nj2; };
  add2(d_in[29], cW3b, 256);
  add2(d_in[31], cW4b, 128);
  add2(d_in[32], coW,  128);
  add2(d_in[33], cob,  1);
  k_cvt_all<<<dim3(4, nj2), 256, 0, stream>>>(J2, flagp);

  // decoder Wsum = Wih + Whh (xin == h_prev in the reference recurrence)
  k_addw<<<(512*128 + 255)/256, 256, 0, stream>>>(cdWih, cdWhh, cdWsum, 512*128);

  // lstm1
  k_gemm<<<dim3(64,8,1), 256, 0, stream>>>(x0, 64, cl1Wih, 64, cl1b, Zf, 512, 64, 0, 0, 0, flagp);
  k_rec<<<64, 512, 0, stream>>>(Zf, Zf, cl1Whh, cl1Whh, h1, 128, 0, 0, nullptr, nullptr, 0, 512, nullptr);

  // biLSTM 2 (f+b input GEMM merged: N=1024, shared A)
  k_gemm<<<dim3(64,16,1), 256, 0, stream>>>(h1, 128, c2Wih, 128, c2bias, Z2, 1024, 128, 0, 0, 0, flagp);
  k_rec<<<128, 512, 0, stream>>>(Z2, Z2 + 512, c2fWhh, c2bWhh, x2, 256, 0, 128, nullptr, nullptr, 0, 1024, nullptr);

  // biLSTM 3 (merged)
  k_gemm<<<dim3(64,16,1), 256, 0, stream>>>(x2, 256, c3Wih, 256, c3bias, Z2, 1024, 256, 0, 0, 0, flagp);
  k_rec<<<128, 512, 0, stream>>>(Z2, Z2 + 512, c3fWhh, c3bWhh, x3, 256, 0, 128, nullptr, nullptr, 0, 1024, nullptr);

  // encoder
  k_gemm<<<dim3(64,8,1), 256, 0, stream>>>(x3, 256, ceWih, 256, ceb, Zf, 512, 256, 0, 0, 0, flagp);
  k_rec<<<64, 512, 0, stream>>>(Zf, Zf, ceWhh, ceWhh, enco, 128, 0, 0, nullptr, nullptr, 0, 512, ec);

  // decoder recurrence (attention-independent): h0 = enco[63], c0 = ec, Z = bias
  k_rec<<<64, 512, 0, stream>>>(cdb, cdb, cdWsum, cdWsum, Hdec, 128, 0, 0,
                                enco + (size_t)63*64*128, ec, 1, 512, nullptr);

  // merged projection: [enco;Hdec] @ attW^T -> [encp;Hprj]  (M=8192)
  k_gemm<<<dim3(128,2,1), 256, 0, stream>>>(enco, 128, cattW, 128, nullptr, encp, 128, 128, 0, 0, 0, flagp);

  // attention (parallel over 64 b x 4 t-slices) -> flat [64, 16384]
  k_att<<<dim3(64,4), 256, 0, stream>>>(enco, encp, Hdec, Hprj, cattw, flat);

  // MLP (split-K raised for occupancy: W1 z=64 -> 1024 blocks)
  k_init<<<(64*1024+255)/256, 256, 0, stream>>>(cW1b, a1, 64*1024, 1023);
  k_gemm<<<dim3(1,16,64), 256, 0, stream>>>(flat, 16384, d_in[24], 16384, nullptr, a1, 1024, 16384, 0, 1, 1, flagp);
  k_init<<<(64*512+255)/256, 256, 0, stream>>>(cW2b, a2, 64*512, 511);
  k_gemm<<<dim3(1,8,16), 256, 0, stream>>>(a1, 1024, d_in[26], 1024, nullptr, a2, 512, 1024, 1, 1, 1, flagp);
  k_init<<<(64*256+255)/256, 256, 0, stream>>>(cW3b, a3, 64*256, 255);
  k_gemm<<<dim3(1,4,8), 256, 0, stream>>>(a2, 512, d_in[28], 512, nullptr, a3, 256, 512, 1, 1, 1, flagp);
  k_init<<<(64*128+255)/256, 256, 0, stream>>>(cW4b, a4, 64*128, 127);
  k_gemm<<<dim3(1,2,4), 256, 0, stream>>>(a3, 256, d_in[30], 256, nullptr, a4, 128, 256, 1, 1, 1, flagp);

  k_head<<<1, 64, 0, stream>>>(a4, coW, cob, d_out, flagp);
}

// Round 7
// 733.176 us; speedup vs baseline: 1.5927x; 1.0385x over previous
//
#include <hip/hip_runtime.h>
#include <hip/hip_bf16.h>

typedef unsigned int u32;
typedef unsigned short u16;

typedef _Float16 half2_t __attribute__((ext_vector_type(2)));
union H2U { u32 u; half2_t h; };

#if defined(__has_builtin)
#if __has_builtin(__builtin_amdgcn_fdot2)
#define HAS_FDOT2 1
#endif
#endif

__device__ __forceinline__ float bf2f(u32 u) {
  union { u32 i; float f; } v; v.i = u << 16; return v.f;
}
__device__ __forceinline__ float sigf(float x) {
  return 1.0f / (1.0f + __expf(-x));
}
__device__ __forceinline__ float tanhfast(float x) {
  return 2.0f / (1.0f + __expf(-2.0f * x)) - 1.0f;
}
__device__ __forceinline__ u16 f2bf(float f) {
  u32 u = __float_as_uint(f);
  u += 0x7fffu + ((u >> 16) & 1u);
  return (u16)(u >> 16);
}
__device__ __forceinline__ float dot2acc(u32 wu, u32 hu, float acc) {
  H2U w, h; w.u = wu; h.u = hu;
#ifdef HAS_FDOT2
  return __builtin_amdgcn_fdot2(w.h, h.h, acc, false);
#else
  acc = fmaf((float)w.h.x, (float)h.h.x, acc);
  return fmaf((float)w.h.y, (float)h.h.y, acc);
#endif
}

// ---- runtime dtype detection (bf16 vs fp32 inputs) ----
__global__ void k_detect(const u32* __restrict__ w, int* __restrict__ flag) {
  __shared__ int cnt;
  if (threadIdx.x == 0) cnt = 0;
  __syncthreads();
  int c = 0;
  for (int i = threadIdx.x; i < 8192; i += 256) {
    const u32 lo = w[i] & 0xffffu;
    const u32 e = (lo >> 7) & 0xffu;
    c += (e >= 100u && e <= 140u) ? 1 : 0;
  }
  atomicAdd(&cnt, c);
  __syncthreads();
  if (threadIdx.x == 0) *flag = (cnt > 4915) ? 1 : 0;
}

struct Job { const void* s; float* d; int n; };
struct Jobs { Job j[26]; };

__global__ void k_cvt_all(Jobs J, const int* __restrict__ flag) {
  const Job jb = J.j[blockIdx.y];
  const int isbf = *flag;
  for (int i = blockIdx.x * 256 + threadIdx.x; i < jb.n; i += 32 * 256) {
    jb.d[i] = isbf ? bf2f(((const u16*)jb.s)[i]) : ((const float*)jb.s)[i];
  }
}

__global__ void k_addw(const float* __restrict__ a, const float* __restrict__ b,
                       float* __restrict__ c, int n) {
  int i = blockIdx.x * 256 + threadIdx.x;
  if (i < n) c[i] = a[i] + b[i];
}

__global__ void k_init(const float* __restrict__ bias, float* __restrict__ C, int n, int mask) {
  int i = blockIdx.x * 256 + threadIdx.x;
  if (i < n) C[i] = bias[i & mask];
}

// Pack staged fp32 recurrent weights into per-thread-ordered f16 pairs:
// out[tid*64 + j*16 + kk] = pack_f16(W[r+128j][kq*32+2kk], W[r+128j][kq*32+2kk+1])
// with r = tid>>2, kq = tid&3  (the exact order k_rec consumes).
struct PJobs { const float* s[7]; u32* d[7]; };
__global__ void k_pack(PJobs P) {
  const float* src = P.s[blockIdx.y];
  u32* dst = P.d[blockIdx.y];
  const int i = blockIdx.x * 256 + threadIdx.x;   // 0..32767
  const int tid = i >> 6, rem = i & 63;
  const int j = rem >> 4, kk = rem & 15;
  const int r = tid >> 2, kq = tid & 3;
  const int row = r + 128 * j, col = kq * 32 + 2 * kk;
  H2U v;
  v.h.x = (_Float16)src[row * 128 + col];
  v.h.y = (_Float16)src[row * 128 + col + 1];
  dst[i] = v.u;
}

// C[M,N] (+)= A[M,K] @ W[N,K]^T (+bias). 32-wide K staging, 16 B/lane loads.
__launch_bounds__(256)
__global__ void k_gemm(const float* __restrict__ A, int lda,
                       const void* __restrict__ Wv, int ldw,
                       const float* __restrict__ bias,
                       float* __restrict__ C, int ldc,
                       int K, int actA, int atom, int wfollow,
                       const int* __restrict__ dflag)
{
  __shared__ float As[32][65];
  __shared__ float Ws[32][65];
  const int isbf = wfollow ? *dflag : 0;
  const int tid = threadIdx.x;
  const int tx = tid & 15, ty = tid >> 4;
  const int m0 = blockIdx.x * 64, n0 = blockIdx.y * 64;
  const int kc = K / gridDim.z;
  const int k0 = blockIdx.z * kc;
  const int lr = tid >> 2;
  const int lk = (tid & 3) << 3;
  float acc[4][4] = {{0.f}};
  const float* Ap   = A + (size_t)(m0 + lr) * lda + k0 + lk;
  const u16*   Wp16 = (const u16*)Wv   + (size_t)(n0 + lr) * ldw + k0 + lk;
  const float* Wp32 = (const float*)Wv + (size_t)(n0 + lr) * ldw + k0 + lk;
  for (int kk = 0; kk < kc; kk += 32) {
    float4 av0 = *(const float4*)(Ap + kk);
    float4 av1 = *(const float4*)(Ap + kk + 4);
    float wv[8];
    if (isbf) {
      const uint4 wu = *(const uint4*)(Wp16 + kk);
      wv[0]=bf2f(wu.x & 0xffffu); wv[1]=bf2f(wu.x >> 16);
      wv[2]=bf2f(wu.y & 0xffffu); wv[3]=bf2f(wu.y >> 16);
      wv[4]=bf2f(wu.z & 0xffffu); wv[5]=bf2f(wu.z >> 16);
      wv[6]=bf2f(wu.w & 0xffffu); wv[7]=bf2f(wu.w >> 16);
    } else {
      const float4 w0 = *(const float4*)(Wp32 + kk);
      const float4 w1 = *(const float4*)(Wp32 + kk + 4);
      wv[0]=w0.x; wv[1]=w0.y; wv[2]=w0.z; wv[3]=w0.w;
      wv[4]=w1.x; wv[5]=w1.y; wv[6]=w1.z; wv[7]=w1.w;
    }
    if (actA) {
      av0.x = tanhfast(av0.x); av0.y = tanhfast(av0.y);
      av0.z = tanhfast(av0.z); av0.w = tanhfast(av0.w);
      av1.x = tanhfast(av1.x); av1.y = tanhfast(av1.y);
      av1.z = tanhfast(av1.z); av1.w = tanhfast(av1.w);
    }
    __syncthreads();
    As[lk+0][lr] = av0.x; As[lk+1][lr] = av0.y;
    As[lk+2][lr] = av0.z; As[lk+3][lr] = av0.w;
    As[lk+4][lr] = av1.x; As[lk+5][lr] = av1.y;
    As[lk+6][lr] = av1.z; As[lk+7][lr] = av1.w;
    #pragma unroll
    for (int q = 0; q < 8; ++q) Ws[lk+q][lr] = wv[q];
    __syncthreads();
    #pragma unroll
    for (int k = 0; k < 32; ++k) {
      float a[4], w[4];
      #pragma unroll
      for (int i = 0; i < 4; ++i) a[i] = As[k][ty + 16*i];
      #pragma unroll
      for (int j = 0; j < 4; ++j) w[j] = Ws[k][tx + 16*j];
      #pragma unroll
      for (int i = 0; i < 4; ++i)
        #pragma unroll
        for (int j = 0; j < 4; ++j)
          acc[i][j] = fmaf(a[i], w[j], acc[i][j]);
    }
  }
  #pragma unroll
  for (int i = 0; i < 4; ++i) {
    const int m = m0 + ty + 16*i;
    #pragma unroll
    for (int j = 0; j < 4; ++j) {
      const int n = n0 + tx + 16*j;
      if (atom) atomicAdd(&C[(size_t)m*ldc + n], acc[i][j]);
      else {
        const float bv = bias ? bias[n] : 0.0f;
        C[(size_t)m*ldc + n] = acc[i][j] + bv;
      }
    }
  }
}

// Recurrence with f16-packed resident weights (64 VGPRs) + v_dot2_f32_f16.
// thread (r=tid>>2, kq=tid&3) owns rows {r+128j} x k-chunk [kq*32, kq*32+32).
// After the quad shfl reduce EVERY thread holds all 4 gate pre-activations for
// row r -> gates computed redundantly in-register (no zlds, 1 barrier/step,
// double-buffered f16 h in LDS). waves_per_eu(2,2): one block/CU = 2 waves/SIMD
// exactly; stops the allocator from spilling to chase 6 waves/EU (round-6 bug).
__launch_bounds__(512)
__attribute__((amdgpu_waves_per_eu(2, 2)))
__global__ void k_rec(const float* __restrict__ Zf, const float* __restrict__ Zb,
                      const u32* __restrict__ Wf, const u32* __restrict__ Wb,
                      float* __restrict__ HS, int hstride, int offF, int offB,
                      const float* __restrict__ h0, const float* __restrict__ c0,
                      int zmode, int zld, float* __restrict__ Cout)
{
  const int b = blockIdx.x & 63;
  const int dir = blockIdx.x >> 6;
  const float* Z = dir ? Zb : Zf;
  const u32* Wg = dir ? Wb : Wf;
  const int off = dir ? offB : offF;
  const int tid = threadIdx.x;
  const int r = tid >> 2, kq = tid & 3;

  __shared__ __align__(16) u32 hbuf[2][64];   // packed f16 h pairs, double-buffered

  u32 wp[64];
  {
    const uint4* wr = (const uint4*)(Wg + (size_t)tid * 64);
    #pragma unroll
    for (int q = 0; q < 16; ++q) {
      const uint4 u = wr[q];
      wp[q*4+0]=u.x; wp[q*4+1]=u.y; wp[q*4+2]=u.z; wp[q*4+3]=u.w;
    }
  }
  #pragma unroll
  for (int q = 0; q < 64; ++q)
    asm volatile("" : "+v"(wp[q]));

  float creg = c0 ? c0[b*128 + r] : 0.0f;
  if (tid < 64) {
    H2U v;
    if (h0) {
      v.h.x = (_Float16)h0[b*128 + 2*tid];
      v.h.y = (_Float16)h0[b*128 + 2*tid + 1];
    } else {
      v.h.x = (_Float16)0.f; v.h.y = (_Float16)0.f;
    }
    hbuf[0][tid] = v.u;
  }
  float zc[4];
  {
    const float* zp = zmode ? Z : (Z + ((size_t)(dir ? 63 : 0)*64 + b)*zld);
    #pragma unroll
    for (int j = 0; j < 4; ++j) zc[j] = zp[r + 128*j];
  }
  __syncthreads();

  for (int t = 0; t < 64; ++t) {
    const int s = dir ? (63 - t) : t;
    float zn[4] = {0.f,0.f,0.f,0.f};
    if (!zmode && t < 63) {
      const int s2 = dir ? (62 - t) : (t + 1);
      const float* zp = Z + ((size_t)s2*64 + b)*zld;
      #pragma unroll
      for (int j = 0; j < 4; ++j) zn[j] = zp[r + 128*j];
    }
    // read this thread's 16 h pairs (f16x2) from the current buffer
    u32 hh16[16];
    {
      const u32* hp = hbuf[t & 1];
      *(uint4*)&hh16[0]  = *(const uint4*)&hp[kq*16];
      *(uint4*)&hh16[4]  = *(const uint4*)&hp[kq*16 + 4];
      *(uint4*)&hh16[8]  = *(const uint4*)&hp[kq*16 + 8];
      *(uint4*)&hh16[12] = *(const uint4*)&hp[kq*16 + 12];
    }
    float a[4] = {0.f,0.f,0.f,0.f};
    #pragma unroll
    for (int j = 0; j < 4; ++j)
      #pragma unroll
      for (int i = 0; i < 16; ++i)
        a[j] = dot2acc(wp[j*16 + i], hh16[i], a[j]);
    #pragma unroll
    for (int j = 0; j < 4; ++j) {
      a[j] += __shfl_xor(a[j], 1, 64);
      a[j] += __shfl_xor(a[j], 2, 64);
    }
    // gates, redundantly in all 4 quad lanes (identical inputs)
    const float zi = a[0] + zc[0], zf2 = a[1] + zc[1];
    const float zg = a[2] + zc[2], zo = a[3] + zc[3];
    const float cc = sigf(zf2) * creg + sigf(zi) * tanhfast(zg);
    const float hh = sigf(zo) * tanhfast(cc);
    creg = cc;
    const float hn = __shfl_down(hh, 4, 64);  // row r+1's h (same wave: rows 16w..16w+15)
    if (kq == 0) {
      HS[((size_t)s*64 + b)*hstride + off + r] = hh;
      if (!(r & 1)) {
        H2U v; v.h.x = (_Float16)hh; v.h.y = (_Float16)hn;
        hbuf[(t+1) & 1][r >> 1] = v.u;
      }
    }
    __syncthreads();
    if (!zmode) {
      #pragma unroll
      for (int j = 0; j < 4; ++j) zc[j] = zn[j];
    }
  }
  if (Cout != nullptr && tid < 128 && (tid & 3) == 0) {}  // (creg write below)
  if (Cout != nullptr && kq == 0) Cout[b*128 + r] = creg;
}

// Attention, fully parallel over (b, t-slice).
#define TS 132
__launch_bounds__(256, 1)
__global__ void k_att(const float* __restrict__ enco, const float* __restrict__ encp,
                      const float* __restrict__ Hdec, const float* __restrict__ Hproj,
                      const float* __restrict__ attw, float* __restrict__ flat)
{
  const int b = blockIdx.x;
  const int t0 = blockIdx.y * 16;
  const int tid = threadIdx.x;
  __shared__ __align__(16) float ep[64*TS];
  __shared__ __align__(16) float en[64*TS];
  __shared__ __align__(16) float hp[16*TS];
  __shared__ float S[64*17];
  __shared__ float aw[64*17];
  __shared__ __align__(16) float awt[128];

  for (int i = tid; i < 8192; i += 256) {
    const int s = i >> 7, k = i & 127;
    const size_t g = ((size_t)s*64 + b)*128 + k;
    ep[s*TS + k] = encp[g];
    en[s*TS + k] = enco[g];
  }
  for (int i = tid; i < 2048; i += 256) {
    const int t = i >> 7, k = i & 127;
    const size_t g = ((size_t)(t0 + t)*64 + b)*128 + k;
    hp[t*TS + k] = Hproj[g];
    flat[(size_t)b*16384 + (t0 + t)*256 + k] = Hdec[g];
  }
  if (tid < 128) awt[tid] = attw[tid];
  __syncthreads();

  {
    const int t = tid & 15, sg = tid >> 4;
    #pragma unroll
    for (int i = 0; i < 4; ++i) {
      const int s = sg*4 + i;
      float acc = 0.f;
      #pragma unroll 8
      for (int k = 0; k < 128; k += 4) {
        const float4 h4 = *(const float4*)&hp[t*TS + k];
        const float4 e4 = *(const float4*)&ep[s*TS + k];
        const float4 w4 = *(const float4*)&awt[k];
        acc = fmaf(w4.x, tanhfast(h4.x + e4.x), acc);
        acc = fmaf(w4.y, tanhfast(h4.y + e4.y), acc);
        acc = fmaf(w4.z, tanhfast(h4.z + e4.z), acc);
        acc = fmaf(w4.w, tanhfast(h4.w + e4.w), acc);
      }
      S[s*17 + t] = acc;
    }
  }
  __syncthreads();
  if (tid < 16) {
    const int t = tid;
    float m = -1e30f;
    for (int s = 0; s < 64; ++s) m = fmaxf(m, S[s*17 + t]);
    float sum = 0.f;
    for (int s = 0; s < 64; ++s) {
      const float e = __expf(S[s*17 + t] - m);
      aw[s*17 + t] = e;
      sum += e;
    }
    const float inv = 1.0f / sum;
    for (int s = 0; s < 64; ++s) aw[s*17 + t] *= inv;
  }
  __syncthreads();
  {
    const int t = tid >> 4, kg = tid & 15;
    float c0a[8] = {0,0,0,0,0,0,0,0};
    for (int s = 0; s < 64; ++s) {
      const float a = aw[s*17 + t];
      const float4 e0 = *(const float4*)&en[s*TS + kg*8];
      const float4 e1 = *(const float4*)&en[s*TS + kg*8 + 4];
      c0a[0] = fmaf(a, e0.x, c0a[0]);
      c0a[1] = fmaf(a, e0.y, c0a[1]);
      c0a[2] = fmaf(a, e0.z, c0a[2]);
      c0a[3] = fmaf(a, e0.w, c0a[3]);
      c0a[4] = fmaf(a, e1.x, c0a[4]);
      c0a[5] = fmaf(a, e1.y, c0a[5]);
      c0a[6] = fmaf(a, e1.z, c0a[6]);
      c0a[7] = fmaf(a, e1.w, c0a[7]);
    }
    float4 o0 = {c0a[0], c0a[1], c0a[2], c0a[3]};
    float4 o1 = {c0a[4], c0a[5], c0a[6], c0a[7]};
    float* dst = &flat[(size_t)b*16384 + (t0 + t)*256 + 128 + kg*8];
    *(float4*)dst = o0;
    *(float4*)(dst + 4) = o1;
  }
}

__global__ void k_head(const float* __restrict__ a4, const float* __restrict__ outW,
                       const float* __restrict__ outb, void* __restrict__ out,
                       const int* __restrict__ dflag)
{
  const int b = threadIdx.x;
  float acc = outb[0];
  #pragma unroll 8
  for (int k = 0; k < 128; ++k)
    acc = fmaf(outW[k], tanhfast(a4[b*128 + k]), acc);
  if (*dflag) ((u16*)out)[b] = f2bf(acc);
  else        ((float*)out)[b] = acc;
}

extern "C" void kernel_launch(void* const* d_in, const int* in_sizes, int n_in,
                              void* d_out, int out_size, void* d_ws, size_t ws_size,
                              hipStream_t stream)
{
  (void)in_sizes; (void)n_in; (void)out_size; (void)ws_size;

  float* p = (float*)d_ws;
  int*   flagp = (int*)p;    p += 64;
  float* x0    = p; p += 64*64*64;
  float* cl1Wih = p; p += 512*64;
  float* cl1Whh = p; p += 512*128;
  float* cl1b   = p; p += 512;
  float* c2Wih  = p; p += 1024*128;
  float* c2bias = p; p += 1024;
  float* c2fWhh = p; p += 512*128;
  float* c2bWhh = p; p += 512*128;
  float* c3Wih  = p; p += 1024*256;
  float* c3bias = p; p += 1024;
  float* c3fWhh = p; p += 512*128;
  float* c3bWhh = p; p += 512*128;
  float* ceWih  = p; p += 512*256;
  float* ceWhh  = p; p += 512*128;
  float* ceb    = p; p += 512;
  float* cdWih  = p; p += 512*128;
  float* cdWhh  = p; p += 512*128;
  float* cdb    = p; p += 512;
  float* cattW  = p; p += 128*128;
  float* cattw  = p; p += 128;
  float* cW1b   = p; p += 1024;
  float* cW2b   = p; p += 512;
  float* cW3b   = p; p += 256;
  float* cW4b   = p; p += 128;
  float* coW    = p; p += 128;
  float* cob    = p; p += 16;
  float* cdWsum = p; p += 512*128;
  u32* wpL1 = (u32*)p; p += 32768;
  u32* wp2f = (u32*)p; p += 32768;
  u32* wp2b = (u32*)p; p += 32768;
  u32* wp3f = (u32*)p; p += 32768;
  u32* wp3b = (u32*)p; p += 32768;
  u32* wpE  = (u32*)p; p += 32768;
  u32* wpD  = (u32*)p; p += 32768;
  float* Zf   = p; p += 4096*512;
  float* Z2   = p; p += 4096*1024;
  float* h1   = p; p += 4096*128;
  float* x2   = p; p += 4096*256;
  float* x3   = p; p += 4096*256;
  float* enco = p; p += 4096*128;   // enco and Hdec contiguous (merged proj A)
  float* Hdec = p; p += 4096*128;
  float* encp = p; p += 4096*128;   // encp and Hprj contiguous (merged proj C)
  float* Hprj = p; p += 4096*128;
  float* ec   = p; p += 64*128;
  float* flat = p; p += 64*16384;
  float* a1   = p; p += 64*1024;
  float* a2   = p; p += 64*512;
  float* a3   = p; p += 64*256;
  float* a4   = p; p += 64*128;

  k_detect<<<1, 256, 0, stream>>>((const u32*)d_in[2], flagp);

  Jobs J;
  int nj = 0;
  auto add = [&](const void* s, float* d, int n) { J.j[nj].s = s; J.j[nj].d = d; J.j[nj].n = n; ++nj; };
  add(d_in[0],  x0,     64*64*64);
  add(d_in[1],  cl1Wih, 512*64);
  add(d_in[2],  cl1Whh, 512*128);
  add(d_in[3],  cl1b,   512);
  add(d_in[4],  c2Wih,            512*128);
  add(d_in[7],  c2Wih + 512*128,  512*128);
  add(d_in[6],  c2bias,       512);
  add(d_in[9],  c2bias + 512, 512);
  add(d_in[5],  c2fWhh, 512*128);
  add(d_in[8],  c2bWhh, 512*128);
  add(d_in[10], c3Wih,            512*256);
  add(d_in[13], c3Wih + 512*256,  512*256);
  add(d_in[12], c3bias,       512);
  add(d_in[15], c3bias + 512, 512);
  add(d_in[11], c3fWhh, 512*128);
  add(d_in[14], c3bWhh, 512*128);
  add(d_in[16], ceWih,  512*256);
  add(d_in[17], ceWhh,  512*128);
  add(d_in[18], ceb,    512);
  add(d_in[19], cdWih,  512*128);
  add(d_in[20], cdWhh,  512*128);
  add(d_in[21], cdb,    512);
  add(d_in[22], cattW,  128*128);
  add(d_in[23], cattw,  128);
  add(d_in[25], cW1b,   1024);
  add(d_in[27], cW2b,   512);
  k_cvt_all<<<dim3(32, nj), 256, 0, stream>>>(J, flagp);

  Jobs J2;
  int nj2 = 0;
  auto add2 = [&](const void* s, float* d, int n) { J2.j[nj2].s = s; J2.j[nj2].d = d; J2.j[nj2].n = n; ++nj2; };
  add2(d_in[29], cW3b, 256);
  add2(d_in[31], cW4b, 128);
  add2(d_in[32], coW,  128);
  add2(d_in[33], cob,  1);
  k_cvt_all<<<dim3(4, nj2), 256, 0, stream>>>(J2, flagp);

  // decoder Wsum = Wih + Whh (xin == h_prev in the reference recurrence)
  k_addw<<<(512*128 + 255)/256, 256, 0, stream>>>(cdWih, cdWhh, cdWsum, 512*128);

  // pack all recurrent weight matrices into per-thread f16-pair layout
  PJobs P;
  P.s[0] = cl1Whh; P.d[0] = wpL1;
  P.s[1] = c2fWhh; P.d[1] = wp2f;
  P.s[2] = c2bWhh; P.d[2] = wp2b;
  P.s[3] = c3fWhh; P.d[3] = wp3f;
  P.s[4] = c3bWhh; P.d[4] = wp3b;
  P.s[5] = ceWhh;  P.d[5] = wpE;
  P.s[6] = cdWsum; P.d[6] = wpD;
  k_pack<<<dim3(128, 7), 256, 0, stream>>>(P);

  // lstm1
  k_gemm<<<dim3(64,8,1), 256, 0, stream>>>(x0, 64, cl1Wih, 64, cl1b, Zf, 512, 64, 0, 0, 0, flagp);
  k_rec<<<64, 512, 0, stream>>>(Zf, Zf, wpL1, wpL1, h1, 128, 0, 0, nullptr, nullptr, 0, 512, nullptr);

  // biLSTM 2 (f+b input GEMM merged: N=1024, shared A)
  k_gemm<<<dim3(64,16,1), 256, 0, stream>>>(h1, 128, c2Wih, 128, c2bias, Z2, 1024, 128, 0, 0, 0, flagp);
  k_rec<<<128, 512, 0, stream>>>(Z2, Z2 + 512, wp2f, wp2b, x2, 256, 0, 128, nullptr, nullptr, 0, 1024, nullptr);

  // biLSTM 3 (merged)
  k_gemm<<<dim3(64,16,1), 256, 0, stream>>>(x2, 256, c3Wih, 256, c3bias, Z2, 1024, 256, 0, 0, 0, flagp);
  k_rec<<<128, 512, 0, stream>>>(Z2, Z2 + 512, wp3f, wp3b, x3, 256, 0, 128, nullptr, nullptr, 0, 1024, nullptr);

  // encoder
  k_gemm<<<dim3(64,8,1), 256, 0, stream>>>(x3, 256, ceWih, 256, ceb, Zf, 512, 256, 0, 0, 0, flagp);
  k_rec<<<64, 512, 0, stream>>>(Zf, Zf, wpE, wpE, enco, 128, 0, 0, nullptr, nullptr, 0, 512, ec);

  // decoder recurrence (attention-independent): h0 = enco[63], c0 = ec, Z = bias
  k_rec<<<64, 512, 0, stream>>>(cdb, cdb, wpD, wpD, Hdec, 128, 0, 0,
                                enco + (size_t)63*64*128, ec, 1, 512, nullptr);

  // merged projection: [enco;Hdec] @ attW^T -> [encp;Hprj]  (M=8192)
  k_gemm<<<dim3(128,2,1), 256, 0, stream>>>(enco, 128, cattW, 128, nullptr, encp, 128, 128, 0, 0, 0, flagp);

  // attention (parallel over 64 b x 4 t-slices) -> flat [64, 16384]
  k_att<<<dim3(64,4), 256, 0, stream>>>(enco, encp, Hdec, Hprj, cattw, flat);

  // MLP
  k_init<<<(64*1024+255)/256, 256, 0, stream>>>(cW1b, a1, 64*1024, 1023);
  k_gemm<<<dim3(1,16,64), 256, 0, stream>>>(flat, 16384, d_in[24], 16384, nullptr, a1, 1024, 16384, 0, 1, 1, flagp);
  k_init<<<(64*512+255)/256, 256, 0, stream>>>(cW2b, a2, 64*512, 511);
  k_gemm<<<dim3(1,8,16), 256, 0, stream>>>(a1, 1024, d_in[26], 1024, nullptr, a2, 512, 1024, 1, 1, 1, flagp);
  k_init<<<(64*256+255)/256, 256, 0, stream>>>(cW3b, a3, 64*256, 255);
  k_gemm<<<dim3(1,4,8), 256, 0, stream>>>(a2, 512, d_in[28], 512, nullptr, a3, 256, 512, 1, 1, 1, flagp);
  k_init<<<(64*128+255)/256, 256, 0, stream>>>(cW4b, a4, 64*128, 127);
  k_gemm<<<dim3(1,2,4), 256, 0, stream>>>(a3, 256, d_in[30], 256, nullptr, a4, 128, 256, 1, 1, 1, flagp);

  k_head<<<1, 64, 0, stream>>>(a4, coW, cob, d_out, flagp);
}

// Round 8
// 731.920 us; speedup vs baseline: 1.5955x; 1.0017x over previous
//
#include <hip/hip_runtime.h>
#include <hip/hip_bf16.h>

typedef unsigned int u32;
typedef unsigned short u16;

typedef _Float16 half2_t __attribute__((ext_vector_type(2)));
union H2U { u32 u; half2_t h; };

#if defined(__has_builtin)
#if __has_builtin(__builtin_amdgcn_fdot2)
#define HAS_FDOT2 1
#endif
#endif

__device__ __forceinline__ float bf2f(u32 u) {
  union { u32 i; float f; } v; v.i = u << 16; return v.f;
}
__device__ __forceinline__ float sigf(float x) {
  return 1.0f / (1.0f + __expf(-x));
}
__device__ __forceinline__ float tanhfast(float x) {
  return 2.0f / (1.0f + __expf(-2.0f * x)) - 1.0f;
}
__device__ __forceinline__ u16 f2bf(float f) {
  u32 u = __float_as_uint(f);
  u += 0x7fffu + ((u >> 16) & 1u);
  return (u16)(u >> 16);
}
__device__ __forceinline__ float dot2acc(u32 wu, u32 hu, float acc) {
  H2U w, h; w.u = wu; h.u = hu;
#ifdef HAS_FDOT2
  return __builtin_amdgcn_fdot2(w.h, h.h, acc, false);
#else
  acc = fmaf((float)w.h.x, (float)h.h.x, acc);
  return fmaf((float)w.h.y, (float)h.h.y, acc);
#endif
}

// ---- runtime dtype detection (bf16 vs fp32 inputs) ----
__global__ void k_detect(const u32* __restrict__ w, int* __restrict__ flag) {
  __shared__ int cnt;
  if (threadIdx.x == 0) cnt = 0;
  __syncthreads();
  int c = 0;
  for (int i = threadIdx.x; i < 8192; i += 256) {
    const u32 lo = w[i] & 0xffffu;
    const u32 e = (lo >> 7) & 0xffu;
    c += (e >= 100u && e <= 140u) ? 1 : 0;
  }
  atomicAdd(&cnt, c);
  __syncthreads();
  if (threadIdx.x == 0) *flag = (cnt > 4915) ? 1 : 0;
}

struct Job { const void* s; float* d; int n; };
struct Jobs { Job j[26]; };

__global__ void k_cvt_all(Jobs J, const int* __restrict__ flag) {
  const Job jb = J.j[blockIdx.y];
  const int isbf = *flag;
  for (int i = blockIdx.x * 256 + threadIdx.x; i < jb.n; i += 32 * 256) {
    jb.d[i] = isbf ? bf2f(((const u16*)jb.s)[i]) : ((const float*)jb.s)[i];
  }
}

__global__ void k_addw(const float* __restrict__ a, const float* __restrict__ b,
                       float* __restrict__ c, int n) {
  int i = blockIdx.x * 256 + threadIdx.x;
  if (i < n) c[i] = a[i] + b[i];
}

__global__ void k_init(const float* __restrict__ bias, float* __restrict__ C, int n, int mask) {
  int i = blockIdx.x * 256 + threadIdx.x;
  if (i < n) C[i] = bias[i & mask];
}

// Pack staged fp32 recurrent weights into per-thread-ordered f16 pairs.
struct PJobs { const float* s[7]; u32* d[7]; };
__global__ void k_pack(PJobs P) {
  const float* src = P.s[blockIdx.y];
  u32* dst = P.d[blockIdx.y];
  const int i = blockIdx.x * 256 + threadIdx.x;   // 0..32767
  const int tid = i >> 6, rem = i & 63;
  const int j = rem >> 4, kk = rem & 15;
  const int r = tid >> 2, kq = tid & 3;
  const int row = r + 128 * j, col = kq * 32 + 2 * kk;
  H2U v;
  v.h.x = (_Float16)src[row * 128 + col];
  v.h.y = (_Float16)src[row * 128 + col + 1];
  dst[i] = v.u;
}

// C[M,N] (+)= A[M,K] @ W[N,K]^T (+bias). 32-wide K staging, 16 B/lane loads.
__launch_bounds__(256)
__global__ void k_gemm(const float* __restrict__ A, int lda,
                       const void* __restrict__ Wv, int ldw,
                       const float* __restrict__ bias,
                       float* __restrict__ C, int ldc,
                       int K, int actA, int atom, int wfollow,
                       const int* __restrict__ dflag)
{
  __shared__ float As[32][65];
  __shared__ float Ws[32][65];
  const int isbf = wfollow ? *dflag : 0;
  const int tid = threadIdx.x;
  const int tx = tid & 15, ty = tid >> 4;
  const int m0 = blockIdx.x * 64, n0 = blockIdx.y * 64;
  const int kc = K / gridDim.z;
  const int k0 = blockIdx.z * kc;
  const int lr = tid >> 2;
  const int lk = (tid & 3) << 3;
  float acc[4][4] = {{0.f}};
  const float* Ap   = A + (size_t)(m0 + lr) * lda + k0 + lk;
  const u16*   Wp16 = (const u16*)Wv   + (size_t)(n0 + lr) * ldw + k0 + lk;
  const float* Wp32 = (const float*)Wv + (size_t)(n0 + lr) * ldw + k0 + lk;
  for (int kk = 0; kk < kc; kk += 32) {
    float4 av0 = *(const float4*)(Ap + kk);
    float4 av1 = *(const float4*)(Ap + kk + 4);
    float wv[8];
    if (isbf) {
      const uint4 wu = *(const uint4*)(Wp16 + kk);
      wv[0]=bf2f(wu.x & 0xffffu); wv[1]=bf2f(wu.x >> 16);
      wv[2]=bf2f(wu.y & 0xffffu); wv[3]=bf2f(wu.y >> 16);
      wv[4]=bf2f(wu.z & 0xffffu); wv[5]=bf2f(wu.z >> 16);
      wv[6]=bf2f(wu.w & 0xffffu); wv[7]=bf2f(wu.w >> 16);
    } else {
      const float4 w0 = *(const float4*)(Wp32 + kk);
      const float4 w1 = *(const float4*)(Wp32 + kk + 4);
      wv[0]=w0.x; wv[1]=w0.y; wv[2]=w0.z; wv[3]=w0.w;
      wv[4]=w1.x; wv[5]=w1.y; wv[6]=w1.z; wv[7]=w1.w;
    }
    if (actA) {
      av0.x = tanhfast(av0.x); av0.y = tanhfast(av0.y);
      av0.z = tanhfast(av0.z); av0.w = tanhfast(av0.w);
      av1.x = tanhfast(av1.x); av1.y = tanhfast(av1.y);
      av1.z = tanhfast(av1.z); av1.w = tanhfast(av1.w);
    }
    __syncthreads();
    As[lk+0][lr] = av0.x; As[lk+1][lr] = av0.y;
    As[lk+2][lr] = av0.z; As[lk+3][lr] = av0.w;
    As[lk+4][lr] = av1.x; As[lk+5][lr] = av1.y;
    As[lk+6][lr] = av1.z; As[lk+7][lr] = av1.w;
    #pragma unroll
    for (int q = 0; q < 8; ++q) Ws[lk+q][lr] = wv[q];
    __syncthreads();
    #pragma unroll
    for (int k = 0; k < 32; ++k) {
      float a[4], w[4];
      #pragma unroll
      for (int i = 0; i < 4; ++i) a[i] = As[k][ty + 16*i];
      #pragma unroll
      for (int j = 0; j < 4; ++j) w[j] = Ws[k][tx + 16*j];
      #pragma unroll
      for (int i = 0; i < 4; ++i)
        #pragma unroll
        for (int j = 0; j < 4; ++j)
          acc[i][j] = fmaf(a[i], w[j], acc[i][j]);
    }
  }
  #pragma unroll
  for (int i = 0; i < 4; ++i) {
    const int m = m0 + ty + 16*i;
    #pragma unroll
    for (int j = 0; j < 4; ++j) {
      const int n = n0 + tx + 16*j;
      if (atom) atomicAdd(&C[(size_t)m*ldc + n], acc[i][j]);
      else {
        const float bv = bias ? bias[n] : 0.0f;
        C[(size_t)m*ldc + n] = acc[i][j] + bv;
      }
    }
  }
}

// Recurrence, global-free inner loop:
//  - Z staged to LDS up-front (128 KB, bulk-coalesced) -> in-loop reads are DS.
//  - h outputs buffered in the consumed zall row (t-1; barrier-separated, no
//    race), bulk-flushed after the loop -> no vmcnt(0) drain at the per-step
//    barrier (round-7 bottleneck: __syncthreads waits vmcnt(0), ~1900 stall
//    cyc/step from in-loop global load+store).
//  - f16-packed resident weights (64 VGPRs) + v_dot2_f32_f16, as round 7.
__launch_bounds__(512)
__attribute__((amdgpu_waves_per_eu(2, 2)))
__global__ void k_rec(const float* __restrict__ Zf, const float* __restrict__ Zb,
                      const u32* __restrict__ Wf, const u32* __restrict__ Wb,
                      float* __restrict__ HS, int hstride, int offF, int offB,
                      const float* __restrict__ h0, const float* __restrict__ c0,
                      int zmode, int zld, float* __restrict__ Cout)
{
  const int b = blockIdx.x & 63;
  const int dir = blockIdx.x >> 6;
  const float* Z = dir ? Zb : Zf;
  const u32* Wg = dir ? Wb : Wf;
  const int off = dir ? offB : offF;
  const int tid = threadIdx.x;
  const int r = tid >> 2, kq = tid & 3;

  __shared__ __align__(16) float zall[64*512];   // 128 KB: staged Z, then h-out rows
  __shared__ __align__(16) u32 hbuf[2][64];      // packed f16 h, double-buffered
  __shared__ float h0buf[128];

  // --- bulk stage Z into LDS (coalesced float4) ---
  if (!zmode) {
    #pragma unroll
    for (int q = 0; q < 16; ++q) {
      const int fid = tid + 512*q;
      const int s = fid >> 7, c4 = (fid & 127) << 2;
      *(float4*)&zall[s*512 + c4] = *(const float4*)&Z[((size_t)s*64 + b)*zld + c4];
    }
  }

  u32 wp[64];
  {
    const uint4* wr = (const uint4*)(Wg + (size_t)tid * 64);
    #pragma unroll
    for (int q = 0; q < 16; ++q) {
      const uint4 u = wr[q];
      wp[q*4+0]=u.x; wp[q*4+1]=u.y; wp[q*4+2]=u.z; wp[q*4+3]=u.w;
    }
  }
  #pragma unroll
  for (int q = 0; q < 64; ++q)
    asm volatile("" : "+v"(wp[q]));

  float creg = c0 ? c0[b*128 + r] : 0.0f;
  if (tid < 64) {
    H2U v;
    if (h0) {
      v.h.x = (_Float16)h0[b*128 + 2*tid];
      v.h.y = (_Float16)h0[b*128 + 2*tid + 1];
    } else {
      v.h.x = (_Float16)0.f; v.h.y = (_Float16)0.f;
    }
    hbuf[0][tid] = v.u;
  }
  float zcst[4] = {0.f,0.f,0.f,0.f};
  if (zmode) {
    #pragma unroll
    for (int j = 0; j < 4; ++j) zcst[j] = Z[r + 128*j];
  }
  __syncthreads();

  for (int t = 0; t < 64; ++t) {
    const int s = dir ? (63 - t) : t;
    float zc[4];
    if (zmode) {
      #pragma unroll
      for (int j = 0; j < 4; ++j) zc[j] = zcst[j];
    } else {
      #pragma unroll
      for (int j = 0; j < 4; ++j) zc[j] = zall[s*512 + r + 128*j];
    }
    u32 hh16[16];
    {
      const u32* hp = hbuf[t & 1];
      *(uint4*)&hh16[0]  = *(const uint4*)&hp[kq*16];
      *(uint4*)&hh16[4]  = *(const uint4*)&hp[kq*16 + 4];
      *(uint4*)&hh16[8]  = *(const uint4*)&hp[kq*16 + 8];
      *(uint4*)&hh16[12] = *(const uint4*)&hp[kq*16 + 12];
    }
    float a[4] = {0.f,0.f,0.f,0.f};
    #pragma unroll
    for (int j = 0; j < 4; ++j)
      #pragma unroll
      for (int i = 0; i < 16; ++i)
        a[j] = dot2acc(wp[j*16 + i], hh16[i], a[j]);
    #pragma unroll
    for (int j = 0; j < 4; ++j) {
      a[j] += __shfl_xor(a[j], 1, 64);
      a[j] += __shfl_xor(a[j], 2, 64);
    }
    const float zi = a[0] + zc[0], zf2 = a[1] + zc[1];
    const float zg = a[2] + zc[2], zo = a[3] + zc[3];
    const float cc = sigf(zf2) * creg + sigf(zi) * tanhfast(zg);
    const float hh = sigf(zo) * tanhfast(cc);
    creg = cc;
    const float hn = __shfl_down(hh, 4, 64);
    if (kq == 0) {
      if (t == 0) h0buf[r] = hh;
      else        zall[(t-1)*512 + r] = hh;   // row t-1 consumed last step (barrier-separated)
      if (!(r & 1)) {
        H2U v; v.h.x = (_Float16)hh; v.h.y = (_Float16)hn;
        hbuf[(t+1) & 1][r >> 1] = v.u;
      }
    }
    __syncthreads();
  }

  // --- bulk flush h history to global (coalesced within rows) ---
  for (int i = tid; i < 8192; i += 512) {
    const int t = i >> 7, k = i & 127;
    const int s = dir ? (63 - t) : t;
    const float v = (t == 0) ? h0buf[k] : zall[(t-1)*512 + k];
    HS[((size_t)s*64 + b)*hstride + off + k] = v;
  }
  if (Cout != nullptr && kq == 0) Cout[b*128 + r] = creg;
}

// Attention, fully parallel over (b, t-slice).
#define TS 132
__launch_bounds__(256, 1)
__global__ void k_att(const float* __restrict__ enco, const float* __restrict__ encp,
                      const float* __restrict__ Hdec, const float* __restrict__ Hproj,
                      const float* __restrict__ attw, float* __restrict__ flat)
{
  const int b = blockIdx.x;
  const int t0 = blockIdx.y * 16;
  const int tid = threadIdx.x;
  __shared__ __align__(16) float ep[64*TS];
  __shared__ __align__(16) float en[64*TS];
  __shared__ __align__(16) float hp[16*TS];
  __shared__ float S[64*17];
  __shared__ float aw[64*17];
  __shared__ __align__(16) float awt[128];

  for (int i = tid; i < 8192; i += 256) {
    const int s = i >> 7, k = i & 127;
    const size_t g = ((size_t)s*64 + b)*128 + k;
    ep[s*TS + k] = encp[g];
    en[s*TS + k] = enco[g];
  }
  for (int i = tid; i < 2048; i += 256) {
    const int t = i >> 7, k = i & 127;
    const size_t g = ((size_t)(t0 + t)*64 + b)*128 + k;
    hp[t*TS + k] = Hproj[g];
    flat[(size_t)b*16384 + (t0 + t)*256 + k] = Hdec[g];
  }
  if (tid < 128) awt[tid] = attw[tid];
  __syncthreads();

  {
    const int t = tid & 15, sg = tid >> 4;
    #pragma unroll
    for (int i = 0; i < 4; ++i) {
      const int s = sg*4 + i;
      float acc = 0.f;
      #pragma unroll 8
      for (int k = 0; k < 128; k += 4) {
        const float4 h4 = *(const float4*)&hp[t*TS + k];
        const float4 e4 = *(const float4*)&ep[s*TS + k];
        const float4 w4 = *(const float4*)&awt[k];
        acc = fmaf(w4.x, tanhfast(h4.x + e4.x), acc);
        acc = fmaf(w4.y, tanhfast(h4.y + e4.y), acc);
        acc = fmaf(w4.z, tanhfast(h4.z + e4.z), acc);
        acc = fmaf(w4.w, tanhfast(h4.w + e4.w), acc);
      }
      S[s*17 + t] = acc;
    }
  }
  __syncthreads();
  if (tid < 16) {
    const int t = tid;
    float m = -1e30f;
    for (int s = 0; s < 64; ++s) m = fmaxf(m, S[s*17 + t]);
    float sum = 0.f;
    for (int s = 0; s < 64; ++s) {
      const float e = __expf(S[s*17 + t] - m);
      aw[s*17 + t] = e;
      sum += e;
    }
    const float inv = 1.0f / sum;
    for (int s = 0; s < 64; ++s) aw[s*17 + t] *= inv;
  }
  __syncthreads();
  {
    const int t = tid >> 4, kg = tid & 15;
    float c0a[8] = {0,0,0,0,0,0,0,0};
    for (int s = 0; s < 64; ++s) {
      const float a = aw[s*17 + t];
      const float4 e0 = *(const float4*)&en[s*TS + kg*8];
      const float4 e1 = *(const float4*)&en[s*TS + kg*8 + 4];
      c0a[0] = fmaf(a, e0.x, c0a[0]);
      c0a[1] = fmaf(a, e0.y, c0a[1]);
      c0a[2] = fmaf(a, e0.z, c0a[2]);
      c0a[3] = fmaf(a, e0.w, c0a[3]);
      c0a[4] = fmaf(a, e1.x, c0a[4]);
      c0a[5] = fmaf(a, e1.y, c0a[5]);
      c0a[6] = fmaf(a, e1.z, c0a[6]);
      c0a[7] = fmaf(a, e1.w, c0a[7]);
    }
    float4 o0 = {c0a[0], c0a[1], c0a[2], c0a[3]};
    float4 o1 = {c0a[4], c0a[5], c0a[6], c0a[7]};
    float* dst = &flat[(size_t)b*16384 + (t0 + t)*256 + 128 + kg*8];
    *(float4*)dst = o0;
    *(float4*)(dst + 4) = o1;
  }
}

__global__ void k_head(const float* __restrict__ a4, const float* __restrict__ outW,
                       const float* __restrict__ outb, void* __restrict__ out,
                       const int* __restrict__ dflag)
{
  const int b = threadIdx.x;
  float acc = outb[0];
  #pragma unroll 8
  for (int k = 0; k < 128; ++k)
    acc = fmaf(outW[k], tanhfast(a4[b*128 + k]), acc);
  if (*dflag) ((u16*)out)[b] = f2bf(acc);
  else        ((float*)out)[b] = acc;
}

extern "C" void kernel_launch(void* const* d_in, const int* in_sizes, int n_in,
                              void* d_out, int out_size, void* d_ws, size_t ws_size,
                              hipStream_t stream)
{
  (void)in_sizes; (void)n_in; (void)out_size; (void)ws_size;

  float* p = (float*)d_ws;
  int*   flagp = (int*)p;    p += 64;
  float* x0    = p; p += 64*64*64;
  float* cl1Wih = p; p += 512*64;
  float* cl1Whh = p; p += 512*128;
  float* cl1b   = p; p += 512;
  float* c2Wih  = p; p += 1024*128;
  float* c2bias = p; p += 1024;
  float* c2fWhh = p; p += 512*128;
  float* c2bWhh = p; p += 512*128;
  float* c3Wih  = p; p += 1024*256;
  float* c3bias = p; p += 1024;
  float* c3fWhh = p; p += 512*128;
  float* c3bWhh = p; p += 512*128;
  float* ceWih  = p; p += 512*256;
  float* ceWhh  = p; p += 512*128;
  float* ceb    = p; p += 512;
  float* cdWih  = p; p += 512*128;
  float* cdWhh  = p; p += 512*128;
  float* cdb    = p; p += 512;
  float* cattW  = p; p += 128*128;
  float* cattw  = p; p += 128;
  float* cW1b   = p; p += 1024;
  float* cW2b   = p; p += 512;
  float* cW3b   = p; p += 256;
  float* cW4b   = p; p += 128;
  float* coW    = p; p += 128;
  float* cob    = p; p += 16;
  float* cdWsum = p; p += 512*128;
  u32* wpL1 = (u32*)p; p += 32768;
  u32* wp2f = (u32*)p; p += 32768;
  u32* wp2b = (u32*)p; p += 32768;
  u32* wp3f = (u32*)p; p += 32768;
  u32* wp3b = (u32*)p; p += 32768;
  u32* wpE  = (u32*)p; p += 32768;
  u32* wpD  = (u32*)p; p += 32768;
  float* Zf   = p; p += 4096*512;
  float* Z2   = p; p += 4096*1024;
  float* h1   = p; p += 4096*128;
  float* x2   = p; p += 4096*256;
  float* x3   = p; p += 4096*256;
  float* enco = p; p += 4096*128;   // enco and Hdec contiguous (merged proj A)
  float* Hdec = p; p += 4096*128;
  float* encp = p; p += 4096*128;   // encp and Hprj contiguous (merged proj C)
  float* Hprj = p; p += 4096*128;
  float* ec   = p; p += 64*128;
  float* flat = p; p += 64*16384;
  float* a1   = p; p += 64*1024;
  float* a2   = p; p += 64*512;
  float* a3   = p; p += 64*256;
  float* a4   = p; p += 64*128;

  k_detect<<<1, 256, 0, stream>>>((const u32*)d_in[2], flagp);

  Jobs J;
  int nj = 0;
  auto add = [&](const void* s, float* d, int n) { J.j[nj].s = s; J.j[nj].d = d; J.j[nj].n = n; ++nj; };
  add(d_in[0],  x0,     64*64*64);
  add(d_in[1],  cl1Wih, 512*64);
  add(d_in[2],  cl1Whh, 512*128);
  add(d_in[3],  cl1b,   512);
  add(d_in[4],  c2Wih,            512*128);
  add(d_in[7],  c2Wih + 512*128,  512*128);
  add(d_in[6],  c2bias,       512);
  add(d_in[9],  c2bias + 512, 512);
  add(d_in[5],  c2fWhh, 512*128);
  add(d_in[8],  c2bWhh, 512*128);
  add(d_in[10], c3Wih,            512*256);
  add(d_in[13], c3Wih + 512*256,  512*256);
  add(d_in[12], c3bias,       512);
  add(d_in[15], c3bias + 512, 512);
  add(d_in[11], c3fWhh, 512*128);
  add(d_in[14], c3bWhh, 512*128);
  add(d_in[16], ceWih,  512*256);
  add(d_in[17], ceWhh,  512*128);
  add(d_in[18], ceb,    512);
  add(d_in[19], cdWih,  512*128);
  add(d_in[20], cdWhh,  512*128);
  add(d_in[21], cdb,    512);
  add(d_in[22], cattW,  128*128);
  add(d_in[23], cattw,  128);
  add(d_in[25], cW1b,   1024);
  add(d_in[27], cW2b,   512);
  k_cvt_all<<<dim3(32, nj), 256, 0, stream>>>(J, flagp);

  Jobs J2;
  int nj2 = 0;
  auto add2 = [&](const void* s, float* d, int n) { J2.j[nj2].s = s; J2.j[nj2].d = d; J2.j[nj2].n = n; ++nj2; };
  add2(d_in[29], cW3b, 256);
  add2(d_in[31], cW4b, 128);
  add2(d_in[32], coW,  128);
  add2(d_in[33], cob,  1);
  k_cvt_all<<<dim3(4, nj2), 256, 0, stream>>>(J2, flagp);

  // decoder Wsum = Wih + Whh (xin == h_prev in the reference recurrence)
  k_addw<<<(512*128 + 255)/256, 256, 0, stream>>>(cdWih, cdWhh, cdWsum, 512*128);

  // pack all recurrent weight matrices into per-thread f16-pair layout
  PJobs P;
  P.s[0] = cl1Whh; P.d[0] = wpL1;
  P.s[1] = c2fWhh; P.d[1] = wp2f;
  P.s[2] = c2bWhh; P.d[2] = wp2b;
  P.s[3] = c3fWhh; P.d[3] = wp3f;
  P.s[4] = c3bWhh; P.d[4] = wp3b;
  P.s[5] = ceWhh;  P.d[5] = wpE;
  P.s[6] = cdWsum; P.d[6] = wpD;
  k_pack<<<dim3(128, 7), 256, 0, stream>>>(P);

  // lstm1
  k_gemm<<<dim3(64,8,1), 256, 0, stream>>>(x0, 64, cl1Wih, 64, cl1b, Zf, 512, 64, 0, 0, 0, flagp);
  k_rec<<<64, 512, 0, stream>>>(Zf, Zf, wpL1, wpL1, h1, 128, 0, 0, nullptr, nullptr, 0, 512, nullptr);

  // biLSTM 2 (f+b input GEMM merged: N=1024, shared A)
  k_gemm<<<dim3(64,16,1), 256, 0, stream>>>(h1, 128, c2Wih, 128, c2bias, Z2, 1024, 128, 0, 0, 0, flagp);
  k_rec<<<128, 512, 0, stream>>>(Z2, Z2 + 512, wp2f, wp2b, x2, 256, 0, 128, nullptr, nullptr, 0, 1024, nullptr);

  // biLSTM 3 (merged)
  k_gemm<<<dim3(64,16,1), 256, 0, stream>>>(x2, 256, c3Wih, 256, c3bias, Z2, 1024, 256, 0, 0, 0, flagp);
  k_rec<<<128, 512, 0, stream>>>(Z2, Z2 + 512, wp3f, wp3b, x3, 256, 0, 128, nullptr, nullptr, 0, 1024, nullptr);

  // encoder
  k_gemm<<<dim3(64,8,1), 256, 0, stream>>>(x3, 256, ceWih, 256, ceb, Zf, 512, 256, 0, 0, 0, flagp);
  k_rec<<<64, 512, 0, stream>>>(Zf, Zf, wpE, wpE, enco, 128, 0, 0, nullptr, nullptr, 0, 512, ec);

  // decoder recurrence (attention-independent): h0 = enco[63], c0 = ec, Z = bias
  k_rec<<<64, 512, 0, stream>>>(cdb, cdb, wpD, wpD, Hdec, 128, 0, 0,
                                enco + (size_t)63*64*128, ec, 1, 512, nullptr);

  // merged projection: [enco;Hdec] @ attW^T -> [encp;Hprj]  (M=8192)
  k_gemm<<<dim3(128,2,1), 256, 0, stream>>>(enco, 128, cattW, 128, nullptr, encp, 128, 128, 0, 0, 0, flagp);

  // attention (parallel over 64 b x 4 t-slices) -> flat [64, 16384]
  k_att<<<dim3(64,4), 256, 0, stream>>>(enco, encp, Hdec, Hprj, cattw, flat);

  // MLP
  k_init<<<(64*1024+255)/256, 256, 0, stream>>>(cW1b, a1, 64*1024, 1023);
  k_gemm<<<dim3(1,16,64), 256, 0, stream>>>(flat, 16384, d_in[24], 16384, nullptr, a1, 1024, 16384, 0, 1, 1, flagp);
  k_init<<<(64*512+255)/256, 256, 0, stream>>>(cW2b, a2, 64*512, 511);
  k_gemm<<<dim3(1,8,16), 256, 0, stream>>>(a1, 1024, d_in[26], 1024, nullptr, a2, 512, 1024, 1, 1, 1, flagp);
  k_init<<<(64*256+255)/256, 256, 0, stream>>>(cW3b, a3, 64*256, 255);
  k_gemm<<<dim3(1,4,8), 256, 0, stream>>>(a2, 512, d_in[28], 512, nullptr, a3, 256, 512, 1, 1, 1, flagp);
  k_init<<<(64*128+255)/256, 256, 0, stream>>>(cW4b, a4, 64*128, 127);
  k_gemm<<<dim3(1,2,4), 256, 0, stream>>>(a3, 256, d_in[30], 256, nullptr, a4, 128, 256, 1, 1, 1, flagp);

  k_head<<<1, 64, 0, stream>>>(a4, coW, cob, d_out, flagp);
}